// Round 6
// baseline (233.115 us; speedup 1.0000x reference)
//
#include <hip/hip_runtime.h>

typedef __attribute__((ext_vector_type(8))) short bf16x8;
typedef __attribute__((ext_vector_type(4))) float f32x4;

__device__ __forceinline__ unsigned f2bf(float x) {
  unsigned u = __float_as_uint(x);
  return (u + 0x7fffu + ((u >> 16) & 1u)) >> 16;   // RN-even
}

// ---------------- feat -> bf16 packed copy (uint = 2 consecutive bf16) -------
__global__ __launch_bounds__(256) void cvt_kernel(
    const float* __restrict__ feat, unsigned* __restrict__ fb, int total2) {
  for (int i = blockIdx.x * 256 + threadIdx.x; i < total2; i += gridDim.x * 256) {
    float2 v = ((const float2*)feat)[i];
    fb[i] = f2bf(v.x) | (f2bf(v.y) << 16);
  }
}

// ---------------- Ws, Wn -> bf16 ----------------
__global__ __launch_bounds__(256) void wcvt_kernel(
    const float* __restrict__ Ws, const float* __restrict__ Wn,
    unsigned* __restrict__ wsb, unsigned* __restrict__ wnb) {
  int i = blockIdx.x * 256 + threadIdx.x;
  if (i < 8192) {
    float2 a = ((const float2*)Ws)[i];
    wsb[i] = f2bf(a.x) | (f2bf(a.y) << 16);
    float2 b = ((const float2*)Wn)[i];
    wnb[i] = f2bf(b.x) | (f2bf(b.y) << 16);
  }
}

// ---------------- CSR build ----------------

__global__ __launch_bounds__(256) void deg_kernel(
    const int* __restrict__ dst, int* __restrict__ rowptr, int E) {
  int e = blockIdx.x * 256 + threadIdx.x;
  if (e < E) atomicAdd(&rowptr[dst[e] + 1], 1);
}

__global__ __launch_bounds__(256) void scan1_kernel(
    int* __restrict__ data, int* __restrict__ bsum, int total) {
  __shared__ int tsum[256];
  const int tid = threadIdx.x;
  const int base = blockIdx.x * 1024 + tid * 4;
  int v0 = 0, v1 = 0, v2 = 0, v3 = 0;
  if (base + 3 < total) {
    int4 v = *(const int4*)(data + base);
    v0 = v.x; v1 = v.y; v2 = v.z; v3 = v.w;
  } else {
    if (base + 0 < total) v0 = data[base + 0];
    if (base + 1 < total) v1 = data[base + 1];
    if (base + 2 < total) v2 = data[base + 2];
    if (base + 3 < total) v3 = data[base + 3];
  }
  v1 += v0; v2 += v1; v3 += v2;
  tsum[tid] = v3;
  __syncthreads();
  for (int off = 1; off < 256; off <<= 1) {
    int t = (tid >= off) ? tsum[tid - off] : 0;
    __syncthreads();
    tsum[tid] += t;
    __syncthreads();
  }
  const int excl = (tid > 0) ? tsum[tid - 1] : 0;
  v0 += excl; v1 += excl; v2 += excl; v3 += excl;
  if (base + 3 < total) {
    *(int4*)(data + base) = make_int4(v0, v1, v2, v3);
  } else {
    if (base + 0 < total) data[base + 0] = v0;
    if (base + 1 < total) data[base + 1] = v1;
    if (base + 2 < total) data[base + 2] = v2;
    if (base + 3 < total) data[base + 3] = v3;
  }
  if (tid == 255) bsum[blockIdx.x] = tsum[255];
}

__global__ __launch_bounds__(64) void scan2_kernel(
    const int* __restrict__ bsum, int* __restrict__ bsumEx, int nb) {
  const int lane = threadIdx.x;
  int v = (lane < nb) ? bsum[lane] : 0;
  const int own = v;
  for (int off = 1; off < 64; off <<= 1) {
    int u = __shfl_up(v, off);
    if (lane >= off) v += u;
  }
  if (lane < nb) bsumEx[lane] = v - own;
}

__global__ __launch_bounds__(256) void scan3_kernel(
    int* __restrict__ data, int* __restrict__ cursor,
    const int* __restrict__ bsumEx, int total, int n) {
  const int add = bsumEx[blockIdx.x];
  const int base = blockIdx.x * 1024 + threadIdx.x * 4;
#pragma unroll
  for (int k = 0; k < 4; ++k) {
    int i = base + k;
    if (i < total) {
      int val = data[i] + add;
      data[i] = val;
      if (i < n) cursor[i] = val;
    }
  }
}

// One 4B scattered write per edge: (col << 16) | round(w * 65535).
// atomicExch instead of plain store: the partial-line store would bypass
// L2 write-allocate (one 64B HBM write per edge, measured 54MB r5); the
// atomic mutates the line IN L2, so same-line updates coalesce.
__global__ __launch_bounds__(256) void fill_kernel(
    const int* __restrict__ src, const int* __restrict__ dst,
    const float* __restrict__ ew, int* __restrict__ cursor,
    unsigned* __restrict__ colw, int E) {
  int e = blockIdx.x * 256 + threadIdx.x;
  if (e >= E) return;
  int d = dst[e];
  int pos = atomicAdd(&cursor[d], 1);
  unsigned q = (unsigned)(ew[e] * 65535.0f + 0.5f);
  atomicExch(&colw[pos], ((unsigned)src[e] << 16) | q);
}

// ---------------- gather: agg[d] = mean_e feat_bf16[src_e]*w_e  (f32 out) ----
// One wave per dst node. Lane owns channels {2*lane, 2*lane+1}.
__global__ __launch_bounds__(256) void gather_kernel(
    const unsigned* __restrict__ fb, const int* __restrict__ rowptr,
    const unsigned* __restrict__ colw, float* __restrict__ agg, int n) {
  const int wid = (blockIdx.x * 256 + threadIdx.x) >> 6;
  const int lane = threadIdx.x & 63;
  if (wid >= n) return;
  const int s = rowptr[wid];
  const int e = rowptr[wid + 1];
  float acc0 = 0.f, acc1 = 0.f;
  for (int j0 = s; j0 < e; j0 += 64) {
    const int idx = j0 + lane;
    const unsigned pv = (idx < e) ? colw[idx] : 0u;
    const int cnt = min(64, e - j0);
    for (int t = 0; t < cnt; ++t) {
      const unsigned p = __shfl(pv, t);
      const int c = (int)(p >> 16);
      const float w = (float)(p & 0xffffu) * (1.0f / 65535.0f);
      const unsigned u = fb[(size_t)c * 64 + lane];
      acc0 += __uint_as_float(u << 16) * w;
      acc1 += __uint_as_float(u & 0xffff0000u) * w;
    }
  }
  const float sc = 1.0f / fmaxf((float)(e - s), 1.0f);
  *(float2*)(agg + (size_t)wid * 128 + lane * 2) = make_float2(acc0 * sc, acc1 * sc);
}

// ---------------- fused MFMA GEMM (in-place on d_out) ----------------
// out[r] = feat_bf[r] @ Ws_bf.T + b + aggf32_bf[r] @ Wn_bf.T
__global__ __launch_bounds__(256) void fused_gemm_kernel(
    const ushort* __restrict__ fb,   // feat bf16 [n][128]
    const ushort* __restrict__ wsb,  // Ws bf16 [128][128]
    const ushort* __restrict__ wnb,  // Wn bf16 [128][128]
    const float* __restrict__ bsv,   // bias [128]
    float* __restrict__ out,         // in: agg f32; out: final
    int n) {
  const int lane = threadIdx.x & 63;
  const int wid = (blockIdx.x * 256 + threadIdx.x) >> 6;
  const int row0 = wid * 16;
  if (row0 >= n) return;
  const int rlo = lane & 15;
  const int g = lane >> 4;

  f32x4 acc[8];
#pragma unroll
  for (int ct = 0; ct < 8; ++ct) {
    float bv = bsv[ct * 16 + rlo];
    acc[ct] = (f32x4){bv, bv, bv, bv};
  }

  const int rowA = min(row0 + rlo, n - 1);   // clamp stays inside last strip

#pragma unroll
  for (int kc = 0; kc < 4; ++kc) {
    const int k0 = kc * 32 + g * 8;
    const bf16x8 aself = *(const bf16x8*)(fb + (size_t)rowA * 128 + k0);
    const float4 u0 = *(const float4*)(out + (size_t)rowA * 128 + k0);
    const float4 u1 = *(const float4*)(out + (size_t)rowA * 128 + k0 + 4);
    bf16x8 aagg;
    aagg[0] = (short)f2bf(u0.x); aagg[1] = (short)f2bf(u0.y);
    aagg[2] = (short)f2bf(u0.z); aagg[3] = (short)f2bf(u0.w);
    aagg[4] = (short)f2bf(u1.x); aagg[5] = (short)f2bf(u1.y);
    aagg[6] = (short)f2bf(u1.z); aagg[7] = (short)f2bf(u1.w);
#pragma unroll
    for (int ct = 0; ct < 8; ++ct) {
      const int c = ct * 16 + rlo;
      const bf16x8 bs = *(const bf16x8*)(wsb + (size_t)c * 128 + k0);
      const bf16x8 bn = *(const bf16x8*)(wnb + (size_t)c * 128 + k0);
      acc[ct] = __builtin_amdgcn_mfma_f32_16x16x32_bf16(aself, bs, acc[ct], 0, 0, 0);
      acc[ct] = __builtin_amdgcn_mfma_f32_16x16x32_bf16(aagg, bn, acc[ct], 0, 0, 0);
    }
  }

  // C/D layout: col = lane&15 (+ct*16), row = (lane>>4)*4 + j   [m89-verified]
#pragma unroll
  for (int ct = 0; ct < 8; ++ct) {
#pragma unroll
    for (int j = 0; j < 4; ++j) {
      const int r = row0 + g * 4 + j;
      if (r < n) out[(size_t)r * 128 + ct * 16 + rlo] = acc[ct][j];
    }
  }
}

extern "C" void kernel_launch(void* const* d_in, const int* in_sizes, int n_in,
                              void* d_out, int out_size, void* d_ws, size_t ws_size,
                              hipStream_t stream) {
  const float* feat = (const float*)d_in[0];
  const int* src = (const int*)d_in[1];
  const int* dst = (const int*)d_in[2];
  const float* ew = (const float*)d_in[3];
  const float* Wn = (const float*)d_in[4];
  const float* Ws = (const float*)d_in[5];
  const float* bs = (const float*)d_in[6];
  const int n = in_sizes[0] / 128;
  const int E = in_sizes[1];
  float* out = (float*)d_out;

  // ws layout: colw 3.2MB + rowptr/cursor/bsum ~0.5MB + fb 12.8MB + W 64KB
  char* w = (char*)d_ws;
  size_t off_colw = 0;                                              // E uints
  size_t off_rowptr = (off_colw + (size_t)E * 4 + 255) & ~(size_t)255;           // n+1 ints
  size_t off_cursor = (off_rowptr + (size_t)(n + 1) * 4 + 255) & ~(size_t)255;   // n ints
  size_t off_bsum = (off_cursor + (size_t)n * 4 + 255) & ~(size_t)255;           // 512 ints
  size_t off_fb = (off_bsum + 512 * 4 + 255) & ~(size_t)255;        // n*64 uints
  size_t off_wsb = (off_fb + (size_t)n * 64 * 4 + 255) & ~(size_t)255;  // 8192 uints
  size_t off_wnb = off_wsb + 8192 * 4;                              // 8192 uints
  unsigned* colw = (unsigned*)(w + off_colw);
  int* rowptr = (int*)(w + off_rowptr);
  int* cursor = (int*)(w + off_cursor);
  int* bsum = (int*)(w + off_bsum);
  int* bsumEx = bsum + 256;
  unsigned* fb = (unsigned*)(w + off_fb);
  unsigned* wsb = (unsigned*)(w + off_wsb);
  unsigned* wnb = (unsigned*)(w + off_wnb);

  const int total = n + 1;
  const int nb = (total + 1023) / 1024;

  (void)hipMemsetAsync(rowptr, 0, (size_t)total * sizeof(int), stream);
  cvt_kernel<<<1024, 256, 0, stream>>>(feat, fb, n * 64);
  wcvt_kernel<<<32, 256, 0, stream>>>(Ws, Wn, wsb, wnb);
  deg_kernel<<<(E + 255) / 256, 256, 0, stream>>>(dst, rowptr, E);
  scan1_kernel<<<nb, 256, 0, stream>>>(rowptr, bsum, total);
  scan2_kernel<<<1, 64, 0, stream>>>(bsum, bsumEx, nb);
  scan3_kernel<<<nb, 256, 0, stream>>>(rowptr, cursor, bsumEx, total, n);
  fill_kernel<<<(E + 255) / 256, 256, 0, stream>>>(src, dst, ew, cursor, colw, E);

  // agg (f32) -> d_out
  gather_kernel<<<(n * 64 + 255) / 256, 256, 0, stream>>>(fb, rowptr, colw, out, n);

  // fused: out = feat@Ws.T + b + agg@Wn.T   (in-place on d_out)
  const int nstrips = (n + 15) / 16;
  fused_gemm_kernel<<<(nstrips + 3) / 4, 256, 0, stream>>>(
      (const ushort*)fb, (const ushort*)wsb, (const ushort*)wnb, bs, out, n);
}

// Round 7
// 158.854 us; speedup vs baseline: 1.4675x; 1.4675x over previous
//
#include <hip/hip_runtime.h>

#define CAP 48        // per-node bucket capacity (mean deg 16; overflow handled exactly)
#define OVFCAP 65536

typedef __attribute__((ext_vector_type(8))) short bf16x8;
typedef __attribute__((ext_vector_type(4))) float f32x4;

__device__ __forceinline__ unsigned f2bf(float x) {
  unsigned u = __float_as_uint(x);
  return (u + 0x7fffu + ((u >> 16) & 1u)) >> 16;   // RN-even
}

// ---------------- feat -> bf16 packed copy (uint = 2 consecutive bf16) -------
__global__ __launch_bounds__(256) void cvt_kernel(
    const float* __restrict__ feat, unsigned* __restrict__ fb, int total2) {
  for (int i = blockIdx.x * 256 + threadIdx.x; i < total2; i += gridDim.x * 256) {
    float2 v = ((const float2*)feat)[i];
    fb[i] = f2bf(v.x) | (f2bf(v.y) << 16);
  }
}

// ---------------- Ws, Wn -> bf16 ----------------
__global__ __launch_bounds__(256) void wcvt_kernel(
    const float* __restrict__ Ws, const float* __restrict__ Wn,
    unsigned* __restrict__ wsb, unsigned* __restrict__ wnb) {
  int i = blockIdx.x * 256 + threadIdx.x;
  if (i < 8192) {
    float2 a = ((const float2*)Ws)[i];
    wsb[i] = f2bf(a.x) | (f2bf(a.y) << 16);
    float2 b = ((const float2*)Wn)[i];
    wnb[i] = f2bf(b.x) | (f2bf(b.y) << 16);
  }
}

// ---------------- build: one pass over edges ----------------
// rank = atomicAdd(cnt[d]); slot write (col<<16 | w16) into fixed bucket.
// Overflow (rank >= CAP) appended to exact-fallback list.
__global__ __launch_bounds__(256) void build_kernel(
    const int* __restrict__ src, const int* __restrict__ dst,
    const float* __restrict__ ew, int* __restrict__ cnt,
    unsigned* __restrict__ colw, int* __restrict__ ovfcnt,
    uint2* __restrict__ ovf, int E) {
  int e = blockIdx.x * 256 + threadIdx.x;
  if (e >= E) return;
  int d = dst[e];
  int rank = atomicAdd(&cnt[d], 1);
  float w = ew[e];
  if (rank < CAP) {
    unsigned q = (unsigned)(w * 65535.0f + 0.5f);
    colw[(size_t)d * CAP + rank] = ((unsigned)src[e] << 16) | q;
  } else {
    int p = atomicAdd(ovfcnt, 1);
    if (p < OVFCAP)
      ovf[p] = make_uint2(((unsigned)d << 16) | (unsigned)src[e], __float_as_uint(w));
  }
}

// ---------------- gather: agg[d] = mean_e feat_bf16[src_e]*w_e  (f32 out) ----
// One wave per dst node. Lane owns channels {2*lane, 2*lane+1}.
__global__ __launch_bounds__(256) void gather_kernel(
    const unsigned* __restrict__ fb, const int* __restrict__ cnt,
    const unsigned* __restrict__ colw, float* __restrict__ agg, int n) {
  const int wid = (blockIdx.x * 256 + threadIdx.x) >> 6;
  const int lane = threadIdx.x & 63;
  if (wid >= n) return;
  const int dg = cnt[wid];
  const int m = min(dg, CAP);
  const unsigned* bucket = colw + (size_t)wid * CAP;
  float acc0 = 0.f, acc1 = 0.f;
  for (int j0 = 0; j0 < m; j0 += 64) {
    const int idx = j0 + lane;
    const unsigned pv = (idx < m) ? bucket[idx] : 0u;
    const int e = min(64, m - j0);
    for (int t = 0; t < e; ++t) {
      const unsigned p = __shfl(pv, t);
      const int c = (int)(p >> 16);
      const float w = (float)(p & 0xffffu) * (1.0f / 65535.0f);
      const unsigned u = fb[(size_t)c * 64 + lane];
      acc0 += __uint_as_float(u << 16) * w;
      acc1 += __uint_as_float(u & 0xffff0000u) * w;
    }
  }
  const float sc = 1.0f / fmaxf((float)dg, 1.0f);
  *(float2*)(agg + (size_t)wid * 128 + lane * 2) = make_float2(acc0 * sc, acc1 * sc);
}

// ---------------- overflow fallback (exact; expected empty) ----------------
// One wave per overflow edge: agg[d] += w/deg * feat_bf16[s]  (f32 atomics).
__global__ __launch_bounds__(256) void ovf_kernel(
    const unsigned* __restrict__ fb, const int* __restrict__ cnt,
    const int* __restrict__ ovfcnt, const uint2* __restrict__ ovf,
    float* __restrict__ agg) {
  const int total = min(*ovfcnt, OVFCAP);
  const int nw = (gridDim.x * 256) >> 6;
  const int wid = (blockIdx.x * 256 + threadIdx.x) >> 6;
  const int lane = threadIdx.x & 63;
  for (int i = wid; i < total; i += nw) {
    const uint2 v = ovf[i];
    const int d = (int)(v.x >> 16);
    const int s = (int)(v.x & 0xffffu);
    const float w = __uint_as_float(v.y);
    const float sc = w / fmaxf((float)cnt[d], 1.0f);
    const unsigned u = fb[(size_t)s * 64 + lane];
    atomicAdd(agg + (size_t)d * 128 + lane * 2, __uint_as_float(u << 16) * sc);
    atomicAdd(agg + (size_t)d * 128 + lane * 2 + 1, __uint_as_float(u & 0xffff0000u) * sc);
  }
}

// ---------------- fused MFMA GEMM (in-place on d_out) ----------------
// out[r] = feat_bf[r] @ Ws_bf.T + b + aggf32_bf[r] @ Wn_bf.T
__global__ __launch_bounds__(256) void fused_gemm_kernel(
    const ushort* __restrict__ fb,   // feat bf16 [n][128]
    const ushort* __restrict__ wsb,  // Ws bf16 [128][128]
    const ushort* __restrict__ wnb,  // Wn bf16 [128][128]
    const float* __restrict__ bsv,   // bias [128]
    float* __restrict__ out,         // in: agg f32; out: final
    int n) {
  const int lane = threadIdx.x & 63;
  const int wid = (blockIdx.x * 256 + threadIdx.x) >> 6;
  const int row0 = wid * 16;
  if (row0 >= n) return;
  const int rlo = lane & 15;
  const int g = lane >> 4;

  f32x4 acc[8];
#pragma unroll
  for (int ct = 0; ct < 8; ++ct) {
    float bv = bsv[ct * 16 + rlo];
    acc[ct] = (f32x4){bv, bv, bv, bv};
  }

  const int rowA = min(row0 + rlo, n - 1);   // clamp stays inside last strip

#pragma unroll
  for (int kc = 0; kc < 4; ++kc) {
    const int k0 = kc * 32 + g * 8;
    const bf16x8 aself = *(const bf16x8*)(fb + (size_t)rowA * 128 + k0);
    const float4 u0 = *(const float4*)(out + (size_t)rowA * 128 + k0);
    const float4 u1 = *(const float4*)(out + (size_t)rowA * 128 + k0 + 4);
    bf16x8 aagg;
    aagg[0] = (short)f2bf(u0.x); aagg[1] = (short)f2bf(u0.y);
    aagg[2] = (short)f2bf(u0.z); aagg[3] = (short)f2bf(u0.w);
    aagg[4] = (short)f2bf(u1.x); aagg[5] = (short)f2bf(u1.y);
    aagg[6] = (short)f2bf(u1.z); aagg[7] = (short)f2bf(u1.w);
#pragma unroll
    for (int ct = 0; ct < 8; ++ct) {
      const int c = ct * 16 + rlo;
      const bf16x8 bsw = *(const bf16x8*)(wsb + (size_t)c * 128 + k0);
      const bf16x8 bnw = *(const bf16x8*)(wnb + (size_t)c * 128 + k0);
      acc[ct] = __builtin_amdgcn_mfma_f32_16x16x32_bf16(aself, bsw, acc[ct], 0, 0, 0);
      acc[ct] = __builtin_amdgcn_mfma_f32_16x16x32_bf16(aagg, bnw, acc[ct], 0, 0, 0);
    }
  }

  // C/D layout: col = ct*16 + (lane&15), row = (lane>>4)*4 + j   [m89-verified]
#pragma unroll
  for (int ct = 0; ct < 8; ++ct) {
#pragma unroll
    for (int j = 0; j < 4; ++j) {
      const int r = row0 + g * 4 + j;
      if (r < n) out[(size_t)r * 128 + ct * 16 + rlo] = acc[ct][j];
    }
  }
}

extern "C" void kernel_launch(void* const* d_in, const int* in_sizes, int n_in,
                              void* d_out, int out_size, void* d_ws, size_t ws_size,
                              hipStream_t stream) {
  const float* feat = (const float*)d_in[0];
  const int* src = (const int*)d_in[1];
  const int* dst = (const int*)d_in[2];
  const float* ew = (const float*)d_in[3];
  const float* Wn = (const float*)d_in[4];
  const float* Ws = (const float*)d_in[5];
  const float* bs = (const float*)d_in[6];
  const int n = in_sizes[0] / 128;
  const int E = in_sizes[1];
  float* out = (float*)d_out;

  // ws layout: colw 9.6MB + cnt/ovf ~0.7MB + fb 12.8MB + W 64KB ≈ 23.2MB.
  char* w = (char*)d_ws;
  size_t off_colw = 0;                                              // n*CAP uints
  size_t off_cnt = (off_colw + (size_t)n * CAP * 4 + 255) & ~(size_t)255;   // n ints + 1 (ovfcnt)
  size_t off_ovf = (off_cnt + (size_t)(n + 1) * 4 + 255) & ~(size_t)255;    // OVFCAP uint2
  size_t off_fb = (off_ovf + (size_t)OVFCAP * 8 + 255) & ~(size_t)255;      // n*64 uints
  size_t off_wsb = (off_fb + (size_t)n * 64 * 4 + 255) & ~(size_t)255;      // 8192 uints
  size_t off_wnb = off_wsb + 8192 * 4;                              // 8192 uints
  unsigned* colw = (unsigned*)(w + off_colw);
  int* cnt = (int*)(w + off_cnt);
  int* ovfcnt = cnt + n;
  uint2* ovf = (uint2*)(w + off_ovf);
  unsigned* fb = (unsigned*)(w + off_fb);
  unsigned* wsb = (unsigned*)(w + off_wsb);
  unsigned* wnb = (unsigned*)(w + off_wnb);

  (void)hipMemsetAsync(cnt, 0, (size_t)(n + 1) * sizeof(int), stream);  // cnt + ovfcnt
  cvt_kernel<<<1024, 256, 0, stream>>>(feat, fb, n * 64);
  wcvt_kernel<<<32, 256, 0, stream>>>(Ws, Wn, wsb, wnb);

  build_kernel<<<(E + 255) / 256, 256, 0, stream>>>(src, dst, ew, cnt, colw, ovfcnt, ovf, E);

  // agg (f32) -> d_out
  gather_kernel<<<(n * 64 + 255) / 256, 256, 0, stream>>>(fb, cnt, colw, out, n);
  ovf_kernel<<<32, 256, 0, stream>>>(fb, cnt, ovfcnt, ovf, out);

  // fused: out = feat@Ws.T + b + agg@Wn.T   (in-place on d_out)
  const int nstrips = (n + 15) / 16;
  fused_gemm_kernel<<<(nstrips + 3) / 4, 256, 0, stream>>>(
      (const ushort*)fb, (const ushort*)wsb, (const ushort*)wnb, bs, out, n);
}

// Round 8
// 137.270 us; speedup vs baseline: 1.6982x; 1.1572x over previous
//
#include <hip/hip_runtime.h>

#define CAP 48        // per-node bucket capacity (mean deg 16; overflow handled exactly)
#define OVFCAP 65536

typedef __attribute__((ext_vector_type(8))) short bf16x8;
typedef __attribute__((ext_vector_type(4))) float f32x4;

__device__ __forceinline__ unsigned f2bf(float x) {
  unsigned u = __float_as_uint(x);
  return (u + 0x7fffu + ((u >> 16) & 1u)) >> 16;   // RN-even
}

// ---------------- feat -> bf16 packed copy (uint = 2 consecutive bf16) -------
__global__ __launch_bounds__(256) void cvt_kernel(
    const float* __restrict__ feat, unsigned* __restrict__ fb, int total2) {
  for (int i = blockIdx.x * 256 + threadIdx.x; i < total2; i += gridDim.x * 256) {
    float2 v = ((const float2*)feat)[i];
    fb[i] = f2bf(v.x) | (f2bf(v.y) << 16);
  }
}

// ---------------- Ws, Wn -> bf16 ----------------
__global__ __launch_bounds__(256) void wcvt_kernel(
    const float* __restrict__ Ws, const float* __restrict__ Wn,
    unsigned* __restrict__ wsb, unsigned* __restrict__ wnb) {
  int i = blockIdx.x * 256 + threadIdx.x;
  if (i < 8192) {
    float2 a = ((const float2*)Ws)[i];
    wsb[i] = f2bf(a.x) | (f2bf(a.y) << 16);
    float2 b = ((const float2*)Wn)[i];
    wnb[i] = f2bf(b.x) | (f2bf(b.y) << 16);
  }
}

// ---------------- build: one pass over edges ----------------
__global__ __launch_bounds__(256) void build_kernel(
    const int* __restrict__ src, const int* __restrict__ dst,
    const float* __restrict__ ew, int* __restrict__ cnt,
    unsigned* __restrict__ colw, int* __restrict__ ovfcnt,
    uint2* __restrict__ ovf, int E) {
  int e = blockIdx.x * 256 + threadIdx.x;
  if (e >= E) return;
  int d = dst[e];
  int rank = atomicAdd(&cnt[d], 1);
  float w = ew[e];
  if (rank < CAP) {
    unsigned q = (unsigned)(w * 65535.0f + 0.5f);
    colw[(size_t)d * CAP + rank] = ((unsigned)src[e] << 16) | q;
  } else {
    int p = atomicAdd(ovfcnt, 1);
    if (p < OVFCAP)
      ovf[p] = make_uint2(((unsigned)d << 16) | (unsigned)src[e], __float_as_uint(w));
  }
}

// ---------------- gather: agg[d] = mean_e feat_bf16[src_e]*w_e  (f32 out) ----
// One wave per dst node. Lane owns channels {2*lane, 2*lane+1}.
// CAP<=64: whole bucket loaded once into pv; edge loop unrolled 4-wide so
// 4 independent fb-row loads are in flight (MLP; r7 showed serial-latency-bound).
__global__ __launch_bounds__(256) void gather_kernel(
    const unsigned* __restrict__ fb, const int* __restrict__ cnt,
    const unsigned* __restrict__ colw, float* __restrict__ agg, int n) {
  const int wid = (blockIdx.x * 256 + threadIdx.x) >> 6;
  const int lane = threadIdx.x & 63;
  if (wid >= n) return;
  const int dg = cnt[wid];
  const int m = min(dg, CAP);
  const unsigned pv = (lane < m) ? colw[(size_t)wid * CAP + lane] : 0u;
  float acc0 = 0.f, acc1 = 0.f;
  const float qs = 1.0f / 65535.0f;
  int t = 0;
  for (; t + 4 <= m; t += 4) {
    const unsigned p0 = __shfl(pv, t);
    const unsigned p1 = __shfl(pv, t + 1);
    const unsigned p2 = __shfl(pv, t + 2);
    const unsigned p3 = __shfl(pv, t + 3);
    const unsigned u0 = fb[(size_t)(p0 >> 16) * 64 + lane];
    const unsigned u1 = fb[(size_t)(p1 >> 16) * 64 + lane];
    const unsigned u2 = fb[(size_t)(p2 >> 16) * 64 + lane];
    const unsigned u3 = fb[(size_t)(p3 >> 16) * 64 + lane];
    const float w0 = (float)(p0 & 0xffffu) * qs;
    const float w1 = (float)(p1 & 0xffffu) * qs;
    const float w2 = (float)(p2 & 0xffffu) * qs;
    const float w3 = (float)(p3 & 0xffffu) * qs;
    acc0 += __uint_as_float(u0 << 16) * w0;
    acc1 += __uint_as_float(u0 & 0xffff0000u) * w0;
    acc0 += __uint_as_float(u1 << 16) * w1;
    acc1 += __uint_as_float(u1 & 0xffff0000u) * w1;
    acc0 += __uint_as_float(u2 << 16) * w2;
    acc1 += __uint_as_float(u2 & 0xffff0000u) * w2;
    acc0 += __uint_as_float(u3 << 16) * w3;
    acc1 += __uint_as_float(u3 & 0xffff0000u) * w3;
  }
  for (; t < m; ++t) {
    const unsigned p = __shfl(pv, t);
    const float w = (float)(p & 0xffffu) * qs;
    const unsigned u = fb[(size_t)(p >> 16) * 64 + lane];
    acc0 += __uint_as_float(u << 16) * w;
    acc1 += __uint_as_float(u & 0xffff0000u) * w;
  }
  const float sc = 1.0f / fmaxf((float)dg, 1.0f);
  *(float2*)(agg + (size_t)wid * 128 + lane * 2) = make_float2(acc0 * sc, acc1 * sc);
}

// ---------------- overflow fallback (exact; expected empty) ----------------
__global__ __launch_bounds__(256) void ovf_kernel(
    const unsigned* __restrict__ fb, const int* __restrict__ cnt,
    const int* __restrict__ ovfcnt, const uint2* __restrict__ ovf,
    float* __restrict__ agg) {
  const int total = min(*ovfcnt, OVFCAP);
  const int nw = (gridDim.x * 256) >> 6;
  const int wid = (blockIdx.x * 256 + threadIdx.x) >> 6;
  const int lane = threadIdx.x & 63;
  for (int i = wid; i < total; i += nw) {
    const uint2 v = ovf[i];
    const int d = (int)(v.x >> 16);
    const int s = (int)(v.x & 0xffffu);
    const float w = __uint_as_float(v.y);
    const float sc = w / fmaxf((float)cnt[d], 1.0f);
    const unsigned u = fb[(size_t)s * 64 + lane];
    atomicAdd(agg + (size_t)d * 128 + lane * 2, __uint_as_float(u << 16) * sc);
    atomicAdd(agg + (size_t)d * 128 + lane * 2 + 1, __uint_as_float(u & 0xffff0000u) * sc);
  }
}

// ---------------- fused MFMA GEMM (in-place on d_out) ----------------
// out[r] = feat_bf[r] @ Ws_bf.T + b + aggf32_bf[r] @ Wn_bf.T
__global__ __launch_bounds__(256) void fused_gemm_kernel(
    const ushort* __restrict__ fb,   // feat bf16 [n][128]
    const ushort* __restrict__ wsb,  // Ws bf16 [128][128]
    const ushort* __restrict__ wnb,  // Wn bf16 [128][128]
    const float* __restrict__ bsv,   // bias [128]
    float* __restrict__ out,         // in: agg f32; out: final
    int n) {
  const int lane = threadIdx.x & 63;
  const int wid = (blockIdx.x * 256 + threadIdx.x) >> 6;
  const int row0 = wid * 16;
  if (row0 >= n) return;
  const int rlo = lane & 15;
  const int g = lane >> 4;

  f32x4 acc[8];
#pragma unroll
  for (int ct = 0; ct < 8; ++ct) {
    float bv = bsv[ct * 16 + rlo];
    acc[ct] = (f32x4){bv, bv, bv, bv};
  }

  const int rowA = min(row0 + rlo, n - 1);   // clamp stays inside last strip

#pragma unroll
  for (int kc = 0; kc < 4; ++kc) {
    const int k0 = kc * 32 + g * 8;
    const bf16x8 aself = *(const bf16x8*)(fb + (size_t)rowA * 128 + k0);
    const float4 u0 = *(const float4*)(out + (size_t)rowA * 128 + k0);
    const float4 u1 = *(const float4*)(out + (size_t)rowA * 128 + k0 + 4);
    bf16x8 aagg;
    aagg[0] = (short)f2bf(u0.x); aagg[1] = (short)f2bf(u0.y);
    aagg[2] = (short)f2bf(u0.z); aagg[3] = (short)f2bf(u0.w);
    aagg[4] = (short)f2bf(u1.x); aagg[5] = (short)f2bf(u1.y);
    aagg[6] = (short)f2bf(u1.z); aagg[7] = (short)f2bf(u1.w);
#pragma unroll
    for (int ct = 0; ct < 8; ++ct) {
      const int c = ct * 16 + rlo;
      const bf16x8 bsw = *(const bf16x8*)(wsb + (size_t)c * 128 + k0);
      const bf16x8 bnw = *(const bf16x8*)(wnb + (size_t)c * 128 + k0);
      acc[ct] = __builtin_amdgcn_mfma_f32_16x16x32_bf16(aself, bsw, acc[ct], 0, 0, 0);
      acc[ct] = __builtin_amdgcn_mfma_f32_16x16x32_bf16(aagg, bnw, acc[ct], 0, 0, 0);
    }
  }

  // C/D layout: col = ct*16 + (lane&15), row = (lane>>4)*4 + j   [m89-verified]
#pragma unroll
  for (int ct = 0; ct < 8; ++ct) {
#pragma unroll
    for (int j = 0; j < 4; ++j) {
      const int r = row0 + g * 4 + j;
      if (r < n) out[(size_t)r * 128 + ct * 16 + rlo] = acc[ct][j];
    }
  }
}

extern "C" void kernel_launch(void* const* d_in, const int* in_sizes, int n_in,
                              void* d_out, int out_size, void* d_ws, size_t ws_size,
                              hipStream_t stream) {
  const float* feat = (const float*)d_in[0];
  const int* src = (const int*)d_in[1];
  const int* dst = (const int*)d_in[2];
  const float* ew = (const float*)d_in[3];
  const float* Wn = (const float*)d_in[4];
  const float* Ws = (const float*)d_in[5];
  const float* bs = (const float*)d_in[6];
  const int n = in_sizes[0] / 128;
  const int E = in_sizes[1];
  float* out = (float*)d_out;

  // ws layout: colw 9.6MB + cnt/ovf ~0.7MB + fb 12.8MB + W 64KB ≈ 23.2MB.
  char* w = (char*)d_ws;
  size_t off_colw = 0;                                              // n*CAP uints
  size_t off_cnt = (off_colw + (size_t)n * CAP * 4 + 255) & ~(size_t)255;   // n ints + 1 (ovfcnt)
  size_t off_ovf = (off_cnt + (size_t)(n + 1) * 4 + 255) & ~(size_t)255;    // OVFCAP uint2
  size_t off_fb = (off_ovf + (size_t)OVFCAP * 8 + 255) & ~(size_t)255;      // n*64 uints
  size_t off_wsb = (off_fb + (size_t)n * 64 * 4 + 255) & ~(size_t)255;      // 8192 uints
  size_t off_wnb = off_wsb + 8192 * 4;                              // 8192 uints
  unsigned* colw = (unsigned*)(w + off_colw);
  int* cnt = (int*)(w + off_cnt);
  int* ovfcnt = cnt + n;
  uint2* ovf = (uint2*)(w + off_ovf);
  unsigned* fb = (unsigned*)(w + off_fb);
  unsigned* wsb = (unsigned*)(w + off_wsb);
  unsigned* wnb = (unsigned*)(w + off_wnb);

  (void)hipMemsetAsync(cnt, 0, (size_t)(n + 1) * sizeof(int), stream);  // cnt + ovfcnt
  cvt_kernel<<<1024, 256, 0, stream>>>(feat, fb, n * 64);
  wcvt_kernel<<<32, 256, 0, stream>>>(Ws, Wn, wsb, wnb);

  build_kernel<<<(E + 255) / 256, 256, 0, stream>>>(src, dst, ew, cnt, colw, ovfcnt, ovf, E);

  // agg (f32) -> d_out
  gather_kernel<<<(n * 64 + 255) / 256, 256, 0, stream>>>(fb, cnt, colw, out, n);
  ovf_kernel<<<32, 256, 0, stream>>>(fb, cnt, ovfcnt, ovf, out);

  // fused: out = feat@Ws.T + b + agg@Wn.T   (in-place on d_out)
  const int nstrips = (n + 15) / 16;
  fused_gemm_kernel<<<(nstrips + 3) / 4, 256, 0, stream>>>(
      (const ushort*)fb, (const ushort*)wsb, (const ushort*)wnb, bs, out, n);
}

// Round 9
// 129.142 us; speedup vs baseline: 1.8051x; 1.0629x over previous
//
#include <hip/hip_runtime.h>

#define CAP 48        // per-node bucket capacity (mean deg 16; overflow handled exactly)
#define OVFCAP 65536
#define CHUNK 2048    // edges per chunk in XCD-sliced build

typedef __attribute__((ext_vector_type(8))) short bf16x8;
typedef __attribute__((ext_vector_type(4))) float f32x4;

__device__ __forceinline__ unsigned f2bf(float x) {
  unsigned u = __float_as_uint(x);
  return (u + 0x7fffu + ((u >> 16) & 1u)) >> 16;   // RN-even
}

// ---------------- feat -> bf16 packed copy (uint = 2 consecutive bf16) -------
__global__ __launch_bounds__(256) void cvt_kernel(
    const float* __restrict__ feat, unsigned* __restrict__ fb, int total2) {
  for (int i = blockIdx.x * 256 + threadIdx.x; i < total2; i += gridDim.x * 256) {
    float2 v = ((const float2*)feat)[i];
    fb[i] = f2bf(v.x) | (f2bf(v.y) << 16);
  }
}

// ---------------- Ws, Wn -> bf16 ----------------
__global__ __launch_bounds__(256) void wcvt_kernel(
    const float* __restrict__ Ws, const float* __restrict__ Wn,
    unsigned* __restrict__ wsb, unsigned* __restrict__ wnb) {
  int i = blockIdx.x * 256 + threadIdx.x;
  if (i < 8192) {
    float2 a = ((const float2*)Ws)[i];
    wsb[i] = f2bf(a.x) | (f2bf(a.y) << 16);
    float2 b = ((const float2*)Wn)[i];
    wnb[i] = f2bf(b.x) | (f2bf(b.y) << 16);
  }
}

// ---------------- build: XCD-sliced pass over edges ----------------
// Block 8c+x scans chunk c, keeps only dst in slice x. All writes to a colw
// line then come from ONE XCD's L2 (blockIdx%8 ~ XCD round-robin), so the
// line fills before writeback (r8: random-XCD writes gave 60B/edge HBM).
// Correctness does NOT depend on the XCD mapping — only write locality.
__global__ __launch_bounds__(256) void build_kernel(
    const int* __restrict__ src, const int* __restrict__ dst,
    const float* __restrict__ ew, int* __restrict__ cnt,
    unsigned* __restrict__ colw, int* __restrict__ ovfcnt,
    uint2* __restrict__ ovf, int E, int n) {
  const int x = blockIdx.x & 7;
  const int c = blockIdx.x >> 3;
  const int per = (n + 7) >> 3;
  const int lo = x * per;
  const int hi = min(n, lo + per);
  const int e1 = min(E, (c + 1) * CHUNK);
  for (int e = c * CHUNK + threadIdx.x; e < e1; e += 256) {
    const int d = dst[e];
    if (d < lo || d >= hi) continue;
    const int rank = atomicAdd(&cnt[d], 1);
    const float w = ew[e];
    if (rank < CAP) {
      const unsigned q = (unsigned)(w * 65535.0f + 0.5f);
      colw[(size_t)d * CAP + rank] = ((unsigned)src[e] << 16) | q;
    } else {
      const int p = atomicAdd(ovfcnt, 1);
      if (p < OVFCAP)
        ovf[p] = make_uint2(((unsigned)d << 16) | (unsigned)src[e], __float_as_uint(w));
    }
  }
}

// ---------------- gather: agg[d] = mean_e feat_bf16[src_e]*w_e ----------------
// One wave per dst node; lane owns channels {2*lane, 2*lane+1}.
// Output: PACKED bf16 into d_out viewed as uint rows of stride 128
// (row d bytes [512d, 512d+256)) — numerically identical to f2bf of the
// old f32 agg, halves write+read traffic. 4-wide unroll for MLP (r8).
__global__ __launch_bounds__(256) void gather_kernel(
    const unsigned* __restrict__ fb, const int* __restrict__ cnt,
    const unsigned* __restrict__ colw, unsigned* __restrict__ aggu, int n) {
  const int wid = (blockIdx.x * 256 + threadIdx.x) >> 6;
  const int lane = threadIdx.x & 63;
  if (wid >= n) return;
  const int dg = cnt[wid];
  const int m = min(dg, CAP);
  const unsigned pv = (lane < m) ? colw[(size_t)wid * CAP + lane] : 0u;
  float acc0 = 0.f, acc1 = 0.f;
  const float qs = 1.0f / 65535.0f;
  int t = 0;
  for (; t + 4 <= m; t += 4) {
    const unsigned p0 = __shfl(pv, t);
    const unsigned p1 = __shfl(pv, t + 1);
    const unsigned p2 = __shfl(pv, t + 2);
    const unsigned p3 = __shfl(pv, t + 3);
    const unsigned u0 = fb[(size_t)(p0 >> 16) * 64 + lane];
    const unsigned u1 = fb[(size_t)(p1 >> 16) * 64 + lane];
    const unsigned u2 = fb[(size_t)(p2 >> 16) * 64 + lane];
    const unsigned u3 = fb[(size_t)(p3 >> 16) * 64 + lane];
    const float w0 = (float)(p0 & 0xffffu) * qs;
    const float w1 = (float)(p1 & 0xffffu) * qs;
    const float w2 = (float)(p2 & 0xffffu) * qs;
    const float w3 = (float)(p3 & 0xffffu) * qs;
    acc0 += __uint_as_float(u0 << 16) * w0;
    acc1 += __uint_as_float(u0 & 0xffff0000u) * w0;
    acc0 += __uint_as_float(u1 << 16) * w1;
    acc1 += __uint_as_float(u1 & 0xffff0000u) * w1;
    acc0 += __uint_as_float(u2 << 16) * w2;
    acc1 += __uint_as_float(u2 & 0xffff0000u) * w2;
    acc0 += __uint_as_float(u3 << 16) * w3;
    acc1 += __uint_as_float(u3 & 0xffff0000u) * w3;
  }
  for (; t < m; ++t) {
    const unsigned p = __shfl(pv, t);
    const float w = (float)(p & 0xffffu) * qs;
    const unsigned u = fb[(size_t)(p >> 16) * 64 + lane];
    acc0 += __uint_as_float(u << 16) * w;
    acc1 += __uint_as_float(u & 0xffff0000u) * w;
  }
  const float sc = 1.0f / fmaxf((float)dg, 1.0f);
  aggu[(size_t)wid * 128 + lane] = f2bf(acc0 * sc) | (f2bf(acc1 * sc) << 16);
}

// ---------------- overflow fallback (exact; expected empty) ----------------
// CAS-add onto the packed-bf16 agg row.
__global__ __launch_bounds__(256) void ovf_kernel(
    const unsigned* __restrict__ fb, const int* __restrict__ cnt,
    const int* __restrict__ ovfcnt, const uint2* __restrict__ ovf,
    unsigned* __restrict__ aggu) {
  const int total = min(*ovfcnt, OVFCAP);
  const int nw = (gridDim.x * 256) >> 6;
  const int wid = (blockIdx.x * 256 + threadIdx.x) >> 6;
  const int lane = threadIdx.x & 63;
  for (int i = wid; i < total; i += nw) {
    const uint2 v = ovf[i];
    const int d = (int)(v.x >> 16);
    const int s = (int)(v.x & 0xffffu);
    const float w = __uint_as_float(v.y);
    const float sc = w / fmaxf((float)cnt[d], 1.0f);
    const unsigned u = fb[(size_t)s * 64 + lane];
    const float add0 = __uint_as_float(u << 16) * sc;
    const float add1 = __uint_as_float(u & 0xffff0000u) * sc;
    unsigned* addr = aggu + (size_t)d * 128 + lane;
    unsigned old = *addr, assumed;
    do {
      assumed = old;
      const float a0 = __uint_as_float(assumed << 16) + add0;
      const float a1 = __uint_as_float(assumed & 0xffff0000u) + add1;
      old = atomicCAS(addr, assumed, f2bf(a0) | (f2bf(a1) << 16));
    } while (old != assumed);
  }
}

// ---------------- fused MFMA GEMM (in-place on d_out) ----------------
// out[r] = feat_bf[r] @ Ws_bf.T + b + agg_bf[r] @ Wn_bf.T
// agg read as packed bf16 from d_out (row r bytes [512r,512r+256)), then the
// same strip's rows are overwritten with f32 — same-wave read-before-write.
__global__ __launch_bounds__(256) void fused_gemm_kernel(
    const ushort* __restrict__ fb,     // feat bf16 [n][128]
    const unsigned* __restrict__ aggu, // agg bf16 packed, row stride 128 uints
    const ushort* __restrict__ wsb,    // Ws bf16 [128][128]
    const ushort* __restrict__ wnb,    // Wn bf16 [128][128]
    const float* __restrict__ bsv,     // bias [128]
    float* __restrict__ out,           // final f32 (same buffer as aggu)
    int n) {
  const int lane = threadIdx.x & 63;
  const int wid = (blockIdx.x * 256 + threadIdx.x) >> 6;
  const int row0 = wid * 16;
  if (row0 >= n) return;
  const int rlo = lane & 15;
  const int g = lane >> 4;

  f32x4 acc[8];
#pragma unroll
  for (int ct = 0; ct < 8; ++ct) {
    float bv = bsv[ct * 16 + rlo];
    acc[ct] = (f32x4){bv, bv, bv, bv};
  }

  const int rowA = min(row0 + rlo, n - 1);   // clamp stays inside last strip

#pragma unroll
  for (int kc = 0; kc < 4; ++kc) {
    const int k0 = kc * 32 + g * 8;
    const bf16x8 aself = *(const bf16x8*)(fb + (size_t)rowA * 128 + k0);
    const bf16x8 aagg = *(const bf16x8*)(aggu + (size_t)rowA * 128 + (k0 >> 1));
#pragma unroll
    for (int ct = 0; ct < 8; ++ct) {
      const int c = ct * 16 + rlo;
      const bf16x8 bsw = *(const bf16x8*)(wsb + (size_t)c * 128 + k0);
      const bf16x8 bnw = *(const bf16x8*)(wnb + (size_t)c * 128 + k0);
      acc[ct] = __builtin_amdgcn_mfma_f32_16x16x32_bf16(aself, bsw, acc[ct], 0, 0, 0);
      acc[ct] = __builtin_amdgcn_mfma_f32_16x16x32_bf16(aagg, bnw, acc[ct], 0, 0, 0);
    }
  }

  // C/D layout: col = ct*16 + (lane&15), row = (lane>>4)*4 + j   [m89-verified]
#pragma unroll
  for (int ct = 0; ct < 8; ++ct) {
#pragma unroll
    for (int j = 0; j < 4; ++j) {
      const int r = row0 + g * 4 + j;
      if (r < n) out[(size_t)r * 128 + ct * 16 + rlo] = acc[ct][j];
    }
  }
}

extern "C" void kernel_launch(void* const* d_in, const int* in_sizes, int n_in,
                              void* d_out, int out_size, void* d_ws, size_t ws_size,
                              hipStream_t stream) {
  const float* feat = (const float*)d_in[0];
  const int* src = (const int*)d_in[1];
  const int* dst = (const int*)d_in[2];
  const float* ew = (const float*)d_in[3];
  const float* Wn = (const float*)d_in[4];
  const float* Ws = (const float*)d_in[5];
  const float* bs = (const float*)d_in[6];
  const int n = in_sizes[0] / 128;
  const int E = in_sizes[1];
  float* out = (float*)d_out;
  unsigned* aggu = (unsigned*)d_out;

  // ws layout: colw 9.6MB + cnt/ovf ~0.7MB + fb 12.8MB + W 64KB ≈ 23.2MB.
  char* w = (char*)d_ws;
  size_t off_colw = 0;                                              // n*CAP uints
  size_t off_cnt = (off_colw + (size_t)n * CAP * 4 + 255) & ~(size_t)255;   // n ints + 1 (ovfcnt)
  size_t off_ovf = (off_cnt + (size_t)(n + 1) * 4 + 255) & ~(size_t)255;    // OVFCAP uint2
  size_t off_fb = (off_ovf + (size_t)OVFCAP * 8 + 255) & ~(size_t)255;      // n*64 uints
  size_t off_wsb = (off_fb + (size_t)n * 64 * 4 + 255) & ~(size_t)255;      // 8192 uints
  size_t off_wnb = off_wsb + 8192 * 4;                              // 8192 uints
  unsigned* colw = (unsigned*)(w + off_colw);
  int* cnt = (int*)(w + off_cnt);
  int* ovfcnt = cnt + n;
  uint2* ovf = (uint2*)(w + off_ovf);
  unsigned* fb = (unsigned*)(w + off_fb);
  unsigned* wsb = (unsigned*)(w + off_wsb);
  unsigned* wnb = (unsigned*)(w + off_wnb);

  (void)hipMemsetAsync(cnt, 0, (size_t)(n + 1) * sizeof(int), stream);  // cnt + ovfcnt
  cvt_kernel<<<1024, 256, 0, stream>>>(feat, fb, n * 64);
  wcvt_kernel<<<32, 256, 0, stream>>>(Ws, Wn, wsb, wnb);

  const int nchunk = (E + CHUNK - 1) / CHUNK;
  build_kernel<<<nchunk * 8, 256, 0, stream>>>(src, dst, ew, cnt, colw, ovfcnt, ovf, E, n);

  // agg (packed bf16) -> d_out rows
  gather_kernel<<<(n * 64 + 255) / 256, 256, 0, stream>>>(fb, cnt, colw, aggu, n);
  ovf_kernel<<<32, 256, 0, stream>>>(fb, cnt, ovfcnt, ovf, aggu);

  // fused: out = feat@Ws.T + b + agg@Wn.T   (in-place on d_out)
  const int nstrips = (n + 15) / 16;
  fused_gemm_kernel<<<(nstrips + 3) / 4, 256, 0, stream>>>(
      (const ushort*)fb, aggu, (const ushort*)wsb, (const ushort*)wnb, bs, out, n);
}

// Round 10
// 120.156 us; speedup vs baseline: 1.9401x; 1.0748x over previous
//
#include <hip/hip_runtime.h>

#define CAP 48        // per-node bucket capacity (mean deg 16; overflow handled exactly)
#define OVFCAP 65536
#define BSTRIDE 5120  // records per bin (mean 4096, +16 sigma)

typedef __attribute__((ext_vector_type(8))) short bf16x8;
typedef __attribute__((ext_vector_type(4))) float f32x4;

__device__ __forceinline__ unsigned f2bf(float x) {
  unsigned u = __float_as_uint(x);
  return (u + 0x7fffu + ((u >> 16) & 1u)) >> 16;   // RN-even
}

// ---------------- feat -> bf16 packed copy (uint = 2 consecutive bf16) -------
__global__ __launch_bounds__(256) void cvt_kernel(
    const float* __restrict__ feat, unsigned* __restrict__ fb, int total2) {
  for (int i = blockIdx.x * 256 + threadIdx.x; i < total2; i += gridDim.x * 256) {
    float2 v = ((const float2*)feat)[i];
    fb[i] = f2bf(v.x) | (f2bf(v.y) << 16);
  }
}

// ---------------- Ws, Wn -> bf16 ----------------
__global__ __launch_bounds__(256) void wcvt_kernel(
    const float* __restrict__ Ws, const float* __restrict__ Wn,
    unsigned* __restrict__ wsb, unsigned* __restrict__ wnb) {
  int i = blockIdx.x * 256 + threadIdx.x;
  if (i < 8192) {
    float2 a = ((const float2*)Ws)[i];
    wsb[i] = f2bf(a.x) | (f2bf(a.y) << 16);
    float2 b = ((const float2*)Wn)[i];
    wnb[i] = f2bf(b.x) | (f2bf(b.y) << 16);
  }
}

// ---------------- phase 1: partition edges into 256-node dst bins ----------
// LDS histogram -> one global atomicAdd per (block,bin) -> contiguous runs.
__global__ __launch_bounds__(256) void bin_kernel(
    const int* __restrict__ src, const int* __restrict__ dst,
    const float* __restrict__ ew, int* __restrict__ gbin,
    uint2* __restrict__ binbuf, int* __restrict__ ovfcnt,
    uint2* __restrict__ ovf, int E) {
  __shared__ int lcnt[256];
  __shared__ int lbase[256];
  const int tid = threadIdx.x;
  lcnt[tid] = 0;
  __syncthreads();
  const int e0 = blockIdx.x * 4096;
  const int e1 = min(E, e0 + 4096);
  for (int e = e0 + tid; e < e1; e += 256)
    atomicAdd(&lcnt[dst[e] >> 8], 1);
  __syncthreads();
  lbase[tid] = lcnt[tid] ? atomicAdd(&gbin[tid], lcnt[tid]) : 0;
  lcnt[tid] = 0;
  __syncthreads();
  for (int e = e0 + tid; e < e1; e += 256) {
    const int d = dst[e];
    const int b = d >> 8;
    const int r = atomicAdd(&lcnt[b], 1);
    const int pos = lbase[b] + r;
    const uint2 rec = make_uint2(((unsigned)d << 16) | (unsigned)src[e],
                                 __float_as_uint(ew[e]));
    if (pos < BSTRIDE) {
      binbuf[(size_t)b * BSTRIDE + pos] = rec;
    } else {                       // ~16-sigma event; exact fallback
      int p = atomicAdd(ovfcnt, 1);
      if (p < OVFCAP) ovf[p] = rec;
    }
  }
}

// ---------------- phase 2: bucket one bin in LDS, dump sequentially --------
__global__ __launch_bounds__(256) void bucket_kernel(
    const int* __restrict__ gbin, const uint2* __restrict__ binbuf,
    int* __restrict__ cnt, unsigned* __restrict__ colw,
    int* __restrict__ ovfcnt, uint2* __restrict__ ovf, int n) {
  __shared__ unsigned lbucket[256 * CAP];   // 48 KB
  __shared__ int lcnt[256];
  const int b = blockIdx.x;
  const int tid = threadIdx.x;
  lcnt[tid] = 0;
  __syncthreads();
  const int lo = b << 8;
  const int m = min(gbin[b], BSTRIDE);
  const uint2* bb = binbuf + (size_t)b * BSTRIDE;
  for (int i = tid; i < m; i += 256) {
    const uint2 rec = bb[i];
    const int dl = (int)(rec.x >> 16) & 255;
    const int r = atomicAdd(&lcnt[dl], 1);       // counts ALL edges -> exact deg
    if (r < CAP) {
      const float w = __uint_as_float(rec.y);
      const unsigned q = (unsigned)(w * 65535.0f + 0.5f);
      lbucket[dl * CAP + r] = ((rec.x & 0xffffu) << 16) | q;
    } else {
      int p = atomicAdd(ovfcnt, 1);
      if (p < OVFCAP) ovf[p] = rec;
    }
  }
  __syncthreads();
  const int nn = min(256, n - lo);
  if (tid < nn) cnt[lo + tid] = lcnt[tid];
  const int tot = nn * CAP;
  unsigned* dstp = colw + (size_t)lo * CAP;
  for (int i = tid; i < tot; i += 256) dstp[i] = lbucket[i];  // sequential
}

// ---------------- gather: agg[d] = mean_e feat_bf16[src_e]*w_e ----------------
// One wave per dst node; lane owns channels {2*lane, 2*lane+1}.
// Output packed bf16 into d_out rows (row d bytes [512d,512d+256)).
__global__ __launch_bounds__(256) void gather_kernel(
    const unsigned* __restrict__ fb, const int* __restrict__ cnt,
    const unsigned* __restrict__ colw, unsigned* __restrict__ aggu, int n) {
  const int wid = (blockIdx.x * 256 + threadIdx.x) >> 6;
  const int lane = threadIdx.x & 63;
  if (wid >= n) return;
  const int dg = cnt[wid];
  const int m = min(dg, CAP);
  const unsigned pv = (lane < m) ? colw[(size_t)wid * CAP + lane] : 0u;
  float acc0 = 0.f, acc1 = 0.f;
  const float qs = 1.0f / 65535.0f;
  int t = 0;
  for (; t + 4 <= m; t += 4) {
    const unsigned p0 = __shfl(pv, t);
    const unsigned p1 = __shfl(pv, t + 1);
    const unsigned p2 = __shfl(pv, t + 2);
    const unsigned p3 = __shfl(pv, t + 3);
    const unsigned u0 = fb[(size_t)(p0 >> 16) * 64 + lane];
    const unsigned u1 = fb[(size_t)(p1 >> 16) * 64 + lane];
    const unsigned u2 = fb[(size_t)(p2 >> 16) * 64 + lane];
    const unsigned u3 = fb[(size_t)(p3 >> 16) * 64 + lane];
    const float w0 = (float)(p0 & 0xffffu) * qs;
    const float w1 = (float)(p1 & 0xffffu) * qs;
    const float w2 = (float)(p2 & 0xffffu) * qs;
    const float w3 = (float)(p3 & 0xffffu) * qs;
    acc0 += __uint_as_float(u0 << 16) * w0;
    acc1 += __uint_as_float(u0 & 0xffff0000u) * w0;
    acc0 += __uint_as_float(u1 << 16) * w1;
    acc1 += __uint_as_float(u1 & 0xffff0000u) * w1;
    acc0 += __uint_as_float(u2 << 16) * w2;
    acc1 += __uint_as_float(u2 & 0xffff0000u) * w2;
    acc0 += __uint_as_float(u3 << 16) * w3;
    acc1 += __uint_as_float(u3 & 0xffff0000u) * w3;
  }
  for (; t < m; ++t) {
    const unsigned p = __shfl(pv, t);
    const float w = (float)(p & 0xffffu) * qs;
    const unsigned u = fb[(size_t)(p >> 16) * 64 + lane];
    acc0 += __uint_as_float(u << 16) * w;
    acc1 += __uint_as_float(u & 0xffff0000u) * w;
  }
  const float sc = 1.0f / fmaxf((float)dg, 1.0f);
  aggu[(size_t)wid * 128 + lane] = f2bf(acc0 * sc) | (f2bf(acc1 * sc) << 16);
}

// ---------------- overflow fallback (exact; expected empty) ----------------
__global__ __launch_bounds__(256) void ovf_kernel(
    const unsigned* __restrict__ fb, const int* __restrict__ cnt,
    const int* __restrict__ ovfcnt, const uint2* __restrict__ ovf,
    unsigned* __restrict__ aggu) {
  const int total = min(*ovfcnt, OVFCAP);
  const int nw = (gridDim.x * 256) >> 6;
  const int wid = (blockIdx.x * 256 + threadIdx.x) >> 6;
  const int lane = threadIdx.x & 63;
  for (int i = wid; i < total; i += nw) {
    const uint2 v = ovf[i];
    const int d = (int)(v.x >> 16);
    const int s = (int)(v.x & 0xffffu);
    const float w = __uint_as_float(v.y);
    const float sc = w / fmaxf((float)cnt[d], 1.0f);
    const unsigned u = fb[(size_t)s * 64 + lane];
    const float add0 = __uint_as_float(u << 16) * sc;
    const float add1 = __uint_as_float(u & 0xffff0000u) * sc;
    unsigned* addr = aggu + (size_t)d * 128 + lane;
    unsigned old = *addr, assumed;
    do {
      assumed = old;
      const float a0 = __uint_as_float(assumed << 16) + add0;
      const float a1 = __uint_as_float(assumed & 0xffff0000u) + add1;
      old = atomicCAS(addr, assumed, f2bf(a0) | (f2bf(a1) << 16));
    } while (old != assumed);
  }
}

// ---------------- fused MFMA GEMM (in-place on d_out) ----------------
// out[r] = feat_bf[r] @ Ws_bf.T + b + agg_bf[r] @ Wn_bf.T
__global__ __launch_bounds__(256) void fused_gemm_kernel(
    const ushort* __restrict__ fb,     // feat bf16 [n][128]
    const unsigned* __restrict__ aggu, // agg bf16 packed, row stride 128 uints
    const ushort* __restrict__ wsb,    // Ws bf16 [128][128]
    const ushort* __restrict__ wnb,    // Wn bf16 [128][128]
    const float* __restrict__ bsv,     // bias [128]
    float* __restrict__ out,           // final f32 (same buffer as aggu)
    int n) {
  const int lane = threadIdx.x & 63;
  const int wid = (blockIdx.x * 256 + threadIdx.x) >> 6;
  const int row0 = wid * 16;
  if (row0 >= n) return;
  const int rlo = lane & 15;
  const int g = lane >> 4;

  f32x4 acc[8];
#pragma unroll
  for (int ct = 0; ct < 8; ++ct) {
    float bv = bsv[ct * 16 + rlo];
    acc[ct] = (f32x4){bv, bv, bv, bv};
  }

  const int rowA = min(row0 + rlo, n - 1);   // clamp stays inside last strip

#pragma unroll
  for (int kc = 0; kc < 4; ++kc) {
    const int k0 = kc * 32 + g * 8;
    const bf16x8 aself = *(const bf16x8*)(fb + (size_t)rowA * 128 + k0);
    const bf16x8 aagg = *(const bf16x8*)(aggu + (size_t)rowA * 128 + (k0 >> 1));
#pragma unroll
    for (int ct = 0; ct < 8; ++ct) {
      const int c = ct * 16 + rlo;
      const bf16x8 bsw = *(const bf16x8*)(wsb + (size_t)c * 128 + k0);
      const bf16x8 bnw = *(const bf16x8*)(wnb + (size_t)c * 128 + k0);
      acc[ct] = __builtin_amdgcn_mfma_f32_16x16x32_bf16(aself, bsw, acc[ct], 0, 0, 0);
      acc[ct] = __builtin_amdgcn_mfma_f32_16x16x32_bf16(aagg, bnw, acc[ct], 0, 0, 0);
    }
  }

  // C/D layout: col = ct*16 + (lane&15), row = (lane>>4)*4 + j   [m89-verified]
#pragma unroll
  for (int ct = 0; ct < 8; ++ct) {
#pragma unroll
    for (int j = 0; j < 4; ++j) {
      const int r = row0 + g * 4 + j;
      if (r < n) out[(size_t)r * 128 + ct * 16 + rlo] = acc[ct][j];
    }
  }
}

extern "C" void kernel_launch(void* const* d_in, const int* in_sizes, int n_in,
                              void* d_out, int out_size, void* d_ws, size_t ws_size,
                              hipStream_t stream) {
  const float* feat = (const float*)d_in[0];
  const int* src = (const int*)d_in[1];
  const int* dst = (const int*)d_in[2];
  const float* ew = (const float*)d_in[3];
  const float* Wn = (const float*)d_in[4];
  const float* Ws = (const float*)d_in[5];
  const float* bs = (const float*)d_in[6];
  const int n = in_sizes[0] / 128;
  const int E = in_sizes[1];
  float* out = (float*)d_out;
  unsigned* aggu = (unsigned*)d_out;

  const int nbins = (n + 255) >> 8;

  // ws: colw 9.6MB | cnt n+1+256 | ovf 0.5MB | max(binbuf 8MB, fb 12.8MB) | W 64KB
  // binbuf overlaps fb: bucket consumes binbuf BEFORE cvt writes fb. ~23.2MB.
  char* w = (char*)d_ws;
  size_t off_colw = 0;
  size_t off_cnt = (off_colw + (size_t)n * CAP * 4 + 255) & ~(size_t)255;
  size_t off_ovf = (off_cnt + (size_t)(n + 1 + 256) * 4 + 255) & ~(size_t)255;
  size_t off_fb = (off_ovf + (size_t)OVFCAP * 8 + 255) & ~(size_t)255;
  size_t off_wsb = (off_fb + (size_t)n * 64 * 4 + 255) & ~(size_t)255;
  size_t off_wnb = off_wsb + 8192 * 4;
  unsigned* colw = (unsigned*)(w + off_colw);
  int* cnt = (int*)(w + off_cnt);
  int* ovfcnt = cnt + n;
  int* gbin = cnt + n + 1;                  // 256 ints
  uint2* ovf = (uint2*)(w + off_ovf);
  unsigned* fb = (unsigned*)(w + off_fb);
  uint2* binbuf = (uint2*)(w + off_fb);     // overlaps fb (dead before cvt)
  unsigned* wsb = (unsigned*)(w + off_wsb);
  unsigned* wnb = (unsigned*)(w + off_wnb);

  (void)hipMemsetAsync(ovfcnt, 0, (1 + 256) * sizeof(int), stream);  // ovfcnt+gbin

  const int nchunk = (E + 4095) / 4096;
  bin_kernel<<<nchunk, 256, 0, stream>>>(src, dst, ew, gbin, binbuf, ovfcnt, ovf, E);
  bucket_kernel<<<nbins, 256, 0, stream>>>(gbin, binbuf, cnt, colw, ovfcnt, ovf, n);

  cvt_kernel<<<1024, 256, 0, stream>>>(feat, fb, n * 64);
  wcvt_kernel<<<32, 256, 0, stream>>>(Ws, Wn, wsb, wnb);

  // agg (packed bf16) -> d_out rows
  gather_kernel<<<(n * 64 + 255) / 256, 256, 0, stream>>>(fb, cnt, colw, aggu, n);
  ovf_kernel<<<32, 256, 0, stream>>>(fb, cnt, ovfcnt, ovf, aggu);

  // fused: out = feat@Ws.T + b + agg@Wn.T   (in-place on d_out)
  const int nstrips = (n + 15) / 16;
  fused_gemm_kernel<<<(nstrips + 3) / 4, 256, 0, stream>>>(
      (const ushort*)fb, aggu, (const ushort*)wsb, (const ushort*)wnb, bs, out, n);
}

// Round 11
// 105.553 us; speedup vs baseline: 2.2085x; 1.1383x over previous
//
#include <hip/hip_runtime.h>

#define CAP 48        // per-node bucket capacity (mean deg 16; overflow handled exactly)
#define OVFCAP 65536
#define BSTRIDE 5120  // records per bin (mean 4096, +16 sigma)
#define BINCHUNK 4096 // edges per bin-phase block

typedef __attribute__((ext_vector_type(8))) short bf16x8;
typedef __attribute__((ext_vector_type(4))) float f32x4;

__device__ __forceinline__ unsigned f2bf(float x) {
  unsigned u = __float_as_uint(x);
  return (u + 0x7fffu + ((u >> 16) & 1u)) >> 16;   // RN-even
}

// ---------------- zero: ovfcnt (1) + gbin (256) ----------------
__global__ __launch_bounds__(512) void zero_kernel(int* __restrict__ p) {
  if (threadIdx.x < 257) p[threadIdx.x] = 0;
}

// ---------------- prep: bin | feat->bf16 | W->bf16, one launch -------------
// Blocks [0,nchunk): partition edges into 256-node dst bins (LDS histogram ->
// one global atomicAdd per (block,bin) -> contiguous binbuf runs).
// Blocks [nchunk, nchunk+1024): cvt feat to packed bf16.
// Last 32 blocks: convert Ws/Wn. All three phases are independent; merging
// overlaps edge-stream and feat-stream and cuts 2 launches.
__global__ __launch_bounds__(256) void prep_kernel(
    const int* __restrict__ src, const int* __restrict__ dst,
    const float* __restrict__ ew, int* __restrict__ gbin,
    uint2* __restrict__ binbuf, int* __restrict__ ovfcnt,
    uint2* __restrict__ ovf, int E,
    const float* __restrict__ feat, unsigned* __restrict__ fb, int total2,
    const float* __restrict__ Ws, const float* __restrict__ Wn,
    unsigned* __restrict__ wsb, unsigned* __restrict__ wnb,
    int nchunk) {
  __shared__ int lcnt[256];
  __shared__ int lbase[256];
  const int b = blockIdx.x;
  const int tid = threadIdx.x;
  if (b < nchunk) {
    lcnt[tid] = 0;
    __syncthreads();
    const int e0 = b * BINCHUNK;
    const int e1 = min(E, e0 + BINCHUNK);
    int dreg[BINCHUNK / 256];
    int k = 0;
    for (int e = e0 + tid; e < e1; e += 256) {
      const int d = dst[e];
      dreg[k++] = d;
      atomicAdd(&lcnt[d >> 8], 1);
    }
    __syncthreads();
    lbase[tid] = lcnt[tid] ? atomicAdd(&gbin[tid], lcnt[tid]) : 0;
    lcnt[tid] = 0;
    __syncthreads();
    k = 0;
    for (int e = e0 + tid; e < e1; e += 256) {
      const int d = dreg[k++];
      const int bn = d >> 8;
      const int r = atomicAdd(&lcnt[bn], 1);
      const int pos = lbase[bn] + r;
      const uint2 rec = make_uint2(((unsigned)d << 16) | (unsigned)src[e],
                                   __float_as_uint(ew[e]));
      if (pos < BSTRIDE) {
        binbuf[(size_t)bn * BSTRIDE + pos] = rec;
      } else {                       // ~16-sigma event; exact fallback
        int p = atomicAdd(ovfcnt, 1);
        if (p < OVFCAP) ovf[p] = rec;
      }
    }
  } else if (b < nchunk + 1024) {
    const int bid = b - nchunk;
    for (int i = bid * 256 + tid; i < total2; i += 1024 * 256) {
      float2 v = ((const float2*)feat)[i];
      fb[i] = f2bf(v.x) | (f2bf(v.y) << 16);
    }
  } else {
    const int i = (b - nchunk - 1024) * 256 + tid;
    if (i < 8192) {
      float2 a = ((const float2*)Ws)[i];
      wsb[i] = f2bf(a.x) | (f2bf(a.y) << 16);
      float2 v = ((const float2*)Wn)[i];
      wnb[i] = f2bf(v.x) | (f2bf(v.y) << 16);
    }
  }
}

// ---------------- phase 2: bucket one bin in LDS, dump sequentially --------
__global__ __launch_bounds__(256) void bucket_kernel(
    const int* __restrict__ gbin, const uint2* __restrict__ binbuf,
    int* __restrict__ cnt, unsigned* __restrict__ colw,
    int* __restrict__ ovfcnt, uint2* __restrict__ ovf, int n) {
  __shared__ unsigned lbucket[256 * CAP];   // 48 KB
  __shared__ int lcnt[256];
  const int b = blockIdx.x;
  const int tid = threadIdx.x;
  lcnt[tid] = 0;
  __syncthreads();
  const int lo = b << 8;
  const int m = min(gbin[b], BSTRIDE);
  const uint2* bb = binbuf + (size_t)b * BSTRIDE;
  for (int i = tid; i < m; i += 256) {
    const uint2 rec = bb[i];
    const int dl = (int)(rec.x >> 16) & 255;
    const int r = atomicAdd(&lcnt[dl], 1);       // counts ALL edges -> exact deg
    if (r < CAP) {
      const float w = __uint_as_float(rec.y);
      const unsigned q = (unsigned)(w * 65535.0f + 0.5f);
      lbucket[dl * CAP + r] = ((rec.x & 0xffffu) << 16) | q;
    } else {
      int p = atomicAdd(ovfcnt, 1);
      if (p < OVFCAP) ovf[p] = rec;
    }
  }
  __syncthreads();
  const int nn = min(256, n - lo);
  if (tid < nn) cnt[lo + tid] = lcnt[tid];
  const int tot = nn * CAP;
  unsigned* dstp = colw + (size_t)lo * CAP;
  for (int i = tid; i < tot; i += 256) dstp[i] = lbucket[i];  // sequential
}

// ---------------- gather: agg[d] = mean_e feat_bf16[src_e]*w_e ----------------
// One wave per dst node; lane owns channels {2*lane, 2*lane+1}.
// Packed-bf16 output into d_out rows. 8-wide unroll: 8 independent fb-row
// loads in flight per wave (r10: 4-wide still latency-limited, VGPR=12).
__global__ __launch_bounds__(256) void gather_kernel(
    const unsigned* __restrict__ fb, const int* __restrict__ cnt,
    const unsigned* __restrict__ colw, unsigned* __restrict__ aggu, int n) {
  const int wid = (blockIdx.x * 256 + threadIdx.x) >> 6;
  const int lane = threadIdx.x & 63;
  if (wid >= n) return;
  const int dg = cnt[wid];
  const int m = min(dg, CAP);
  const unsigned pv = (lane < m) ? colw[(size_t)wid * CAP + lane] : 0u;
  float acc0 = 0.f, acc1 = 0.f;
  const float qs = 1.0f / 65535.0f;
  int t = 0;
  for (; t + 8 <= m; t += 8) {
    unsigned p[8], u[8];
#pragma unroll
    for (int i = 0; i < 8; ++i) p[i] = __shfl(pv, t + i);
#pragma unroll
    for (int i = 0; i < 8; ++i) u[i] = fb[(size_t)(p[i] >> 16) * 64 + lane];
#pragma unroll
    for (int i = 0; i < 8; ++i) {
      const float w = (float)(p[i] & 0xffffu) * qs;
      acc0 += __uint_as_float(u[i] << 16) * w;
      acc1 += __uint_as_float(u[i] & 0xffff0000u) * w;
    }
  }
  if (t + 4 <= m) {
    unsigned p[4], u[4];
#pragma unroll
    for (int i = 0; i < 4; ++i) p[i] = __shfl(pv, t + i);
#pragma unroll
    for (int i = 0; i < 4; ++i) u[i] = fb[(size_t)(p[i] >> 16) * 64 + lane];
#pragma unroll
    for (int i = 0; i < 4; ++i) {
      const float w = (float)(p[i] & 0xffffu) * qs;
      acc0 += __uint_as_float(u[i] << 16) * w;
      acc1 += __uint_as_float(u[i] & 0xffff0000u) * w;
    }
    t += 4;
  }
  for (; t < m; ++t) {
    const unsigned p = __shfl(pv, t);
    const float w = (float)(p & 0xffffu) * qs;
    const unsigned u = fb[(size_t)(p >> 16) * 64 + lane];
    acc0 += __uint_as_float(u << 16) * w;
    acc1 += __uint_as_float(u & 0xffff0000u) * w;
  }
  const float sc = 1.0f / fmaxf((float)dg, 1.0f);
  aggu[(size_t)wid * 128 + lane] = f2bf(acc0 * sc) | (f2bf(acc1 * sc) << 16);
}

// ---------------- overflow fallback (exact; expected empty) ----------------
__global__ __launch_bounds__(256) void ovf_kernel(
    const unsigned* __restrict__ fb, const int* __restrict__ cnt,
    const int* __restrict__ ovfcnt, const uint2* __restrict__ ovf,
    unsigned* __restrict__ aggu) {
  const int total = min(*ovfcnt, OVFCAP);
  const int nw = (gridDim.x * 256) >> 6;
  const int wid = (blockIdx.x * 256 + threadIdx.x) >> 6;
  const int lane = threadIdx.x & 63;
  for (int i = wid; i < total; i += nw) {
    const uint2 v = ovf[i];
    const int d = (int)(v.x >> 16);
    const int s = (int)(v.x & 0xffffu);
    const float w = __uint_as_float(v.y);
    const float sc = w / fmaxf((float)cnt[d], 1.0f);
    const unsigned u = fb[(size_t)s * 64 + lane];
    const float add0 = __uint_as_float(u << 16) * sc;
    const float add1 = __uint_as_float(u & 0xffff0000u) * sc;
    unsigned* addr = aggu + (size_t)d * 128 + lane;
    unsigned old = *addr, assumed;
    do {
      assumed = old;
      const float a0 = __uint_as_float(assumed << 16) + add0;
      const float a1 = __uint_as_float(assumed & 0xffff0000u) + add1;
      old = atomicCAS(addr, assumed, f2bf(a0) | (f2bf(a1) << 16));
    } while (old != assumed);
  }
}

// ---------------- fused MFMA GEMM (in-place on d_out) ----------------
// out[r] = feat_bf[r] @ Ws_bf.T + b + agg_bf[r] @ Wn_bf.T
__global__ __launch_bounds__(256) void fused_gemm_kernel(
    const ushort* __restrict__ fb,     // feat bf16 [n][128]
    const unsigned* __restrict__ aggu, // agg bf16 packed, row stride 128 uints
    const ushort* __restrict__ wsb,    // Ws bf16 [128][128]
    const ushort* __restrict__ wnb,    // Wn bf16 [128][128]
    const float* __restrict__ bsv,     // bias [128]
    float* __restrict__ out,           // final f32 (same buffer as aggu)
    int n) {
  const int lane = threadIdx.x & 63;
  const int wid = (blockIdx.x * 256 + threadIdx.x) >> 6;
  const int row0 = wid * 16;
  if (row0 >= n) return;
  const int rlo = lane & 15;
  const int g = lane >> 4;

  f32x4 acc[8];
#pragma unroll
  for (int ct = 0; ct < 8; ++ct) {
    float bv = bsv[ct * 16 + rlo];
    acc[ct] = (f32x4){bv, bv, bv, bv};
  }

  const int rowA = min(row0 + rlo, n - 1);   // clamp stays inside last strip

#pragma unroll
  for (int kc = 0; kc < 4; ++kc) {
    const int k0 = kc * 32 + g * 8;
    const bf16x8 aself = *(const bf16x8*)(fb + (size_t)rowA * 128 + k0);
    const bf16x8 aagg = *(const bf16x8*)(aggu + (size_t)rowA * 128 + (k0 >> 1));
#pragma unroll
    for (int ct = 0; ct < 8; ++ct) {
      const int c = ct * 16 + rlo;
      const bf16x8 bsw = *(const bf16x8*)(wsb + (size_t)c * 128 + k0);
      const bf16x8 bnw = *(const bf16x8*)(wnb + (size_t)c * 128 + k0);
      acc[ct] = __builtin_amdgcn_mfma_f32_16x16x32_bf16(aself, bsw, acc[ct], 0, 0, 0);
      acc[ct] = __builtin_amdgcn_mfma_f32_16x16x32_bf16(aagg, bnw, acc[ct], 0, 0, 0);
    }
  }

  // C/D layout: col = ct*16 + (lane&15), row = (lane>>4)*4 + j   [m89-verified]
#pragma unroll
  for (int ct = 0; ct < 8; ++ct) {
#pragma unroll
    for (int j = 0; j < 4; ++j) {
      const int r = row0 + g * 4 + j;
      if (r < n) out[(size_t)r * 128 + ct * 16 + rlo] = acc[ct][j];
    }
  }
}

extern "C" void kernel_launch(void* const* d_in, const int* in_sizes, int n_in,
                              void* d_out, int out_size, void* d_ws, size_t ws_size,
                              hipStream_t stream) {
  const float* feat = (const float*)d_in[0];
  const int* src = (const int*)d_in[1];
  const int* dst = (const int*)d_in[2];
  const float* ew = (const float*)d_in[3];
  const float* Wn = (const float*)d_in[4];
  const float* Ws = (const float*)d_in[5];
  const float* bs = (const float*)d_in[6];
  const int n = in_sizes[0] / 128;
  const int E = in_sizes[1];
  float* out = (float*)d_out;
  unsigned* aggu = (unsigned*)d_out;

  const int nbins = (n + 255) >> 8;

  // ws: colw 9.6MB | cnt n+1+256 | ovf 0.5MB | max(binbuf 8MB, fb 12.8MB) | W
  // binbuf overlaps fb? NO — prep runs bin and cvt concurrently now, so they
  // must be disjoint: fb gets its own region after binbuf. ~31MB total... too
  // risky vs proven 25.6MB? colw(9.6)+cnt(0.2)+ovf(0.5)+binbuf(8)+fb(12.8)+W(0.06)
  // = 31.2MB. ws_size was >=256MB in r10 (harness restore filled 268MB), safe.
  char* w = (char*)d_ws;
  size_t off_colw = 0;
  size_t off_cnt = (off_colw + (size_t)n * CAP * 4 + 255) & ~(size_t)255;
  size_t off_ovf = (off_cnt + (size_t)(n + 1 + 256) * 4 + 255) & ~(size_t)255;
  size_t off_binbuf = (off_ovf + (size_t)OVFCAP * 8 + 255) & ~(size_t)255;
  size_t off_fb = (off_binbuf + (size_t)256 * BSTRIDE * 8 + 255) & ~(size_t)255;
  size_t off_wsb = (off_fb + (size_t)n * 64 * 4 + 255) & ~(size_t)255;
  size_t off_wnb = off_wsb + 8192 * 4;
  unsigned* colw = (unsigned*)(w + off_colw);
  int* cnt = (int*)(w + off_cnt);
  int* ovfcnt = cnt + n;
  int* gbin = cnt + n + 1;                  // 256 ints
  uint2* ovf = (uint2*)(w + off_ovf);
  uint2* binbuf = (uint2*)(w + off_binbuf);
  unsigned* fb = (unsigned*)(w + off_fb);
  unsigned* wsb = (unsigned*)(w + off_wsb);
  unsigned* wnb = (unsigned*)(w + off_wnb);

  zero_kernel<<<1, 512, 0, stream>>>(ovfcnt);   // ovfcnt + gbin (257 ints)

  const int nchunk = (E + BINCHUNK - 1) / BINCHUNK;
  prep_kernel<<<nchunk + 1024 + 32, 256, 0, stream>>>(
      src, dst, ew, gbin, binbuf, ovfcnt, ovf, E,
      feat, fb, n * 64, Ws, Wn, wsb, wnb, nchunk);

  bucket_kernel<<<nbins, 256, 0, stream>>>(gbin, binbuf, cnt, colw, ovfcnt, ovf, n);

  // agg (packed bf16) -> d_out rows
  gather_kernel<<<(n * 64 + 255) / 256, 256, 0, stream>>>(fb, cnt, colw, aggu, n);
  ovf_kernel<<<32, 256, 0, stream>>>(fb, cnt, ovfcnt, ovf, aggu);

  // fused: out = feat@Ws.T + b + agg@Wn.T   (in-place on d_out)
  const int nstrips = (n + 15) / 16;
  fused_gemm_kernel<<<(nstrips + 3) / 4, 256, 0, stream>>>(
      (const ushort*)fb, aggu, (const ushort*)wsb, (const ushort*)wnb, bs, out, n);
}

// Round 12
// 101.049 us; speedup vs baseline: 2.3069x; 1.0446x over previous
//
#include <hip/hip_runtime.h>

#define CAP 32        // per-node bucket capacity (mean deg 16; overflow handled exactly)
#define OVFCAP 65536
#define BSTRIDE 5120  // records per bin (mean 4096, +16 sigma)
#define BINCHUNK 4096 // edges per bin-phase block

typedef __attribute__((ext_vector_type(8))) short bf16x8;
typedef __attribute__((ext_vector_type(4))) float f32x4;

__device__ __forceinline__ unsigned f2bf(float x) {
  unsigned u = __float_as_uint(x);
  return (u + 0x7fffu + ((u >> 16) & 1u)) >> 16;   // RN-even
}

// ---------------- zero: ovfcnt (1) + gbin (256) ----------------
__global__ __launch_bounds__(512) void zero_kernel(int* __restrict__ p) {
  if (threadIdx.x < 257) p[threadIdx.x] = 0;
}

// ---------------- prep: bin | feat->bf16+fp8 | W->bf16, one launch ---------
// Blocks [0,nchunk): partition edges into 256-node dst bins.
// Blocks [nchunk, nchunk+1024): cvt feat to packed bf16 (fb) AND fp8 (fbq).
// Last 32 blocks: convert Ws/Wn.
__global__ __launch_bounds__(256) void prep_kernel(
    const int* __restrict__ src, const int* __restrict__ dst,
    const float* __restrict__ ew, int* __restrict__ gbin,
    uint2* __restrict__ binbuf, int* __restrict__ ovfcnt,
    uint2* __restrict__ ovf, int E,
    const float* __restrict__ feat, unsigned* __restrict__ fb,
    unsigned* __restrict__ fbq, int total4,
    const float* __restrict__ Ws, const float* __restrict__ Wn,
    unsigned* __restrict__ wsb, unsigned* __restrict__ wnb,
    int nchunk) {
  __shared__ int lcnt[256];
  __shared__ int lbase[256];
  const int b = blockIdx.x;
  const int tid = threadIdx.x;
  if (b < nchunk) {
    lcnt[tid] = 0;
    __syncthreads();
    const int e0 = b * BINCHUNK;
    const int e1 = min(E, e0 + BINCHUNK);
    int dreg[BINCHUNK / 256];
    int k = 0;
    for (int e = e0 + tid; e < e1; e += 256) {
      const int d = dst[e];
      dreg[k++] = d;
      atomicAdd(&lcnt[d >> 8], 1);
    }
    __syncthreads();
    lbase[tid] = lcnt[tid] ? atomicAdd(&gbin[tid], lcnt[tid]) : 0;
    lcnt[tid] = 0;
    __syncthreads();
    k = 0;
    for (int e = e0 + tid; e < e1; e += 256) {
      const int d = dreg[k++];
      const int bn = d >> 8;
      const int r = atomicAdd(&lcnt[bn], 1);
      const int pos = lbase[bn] + r;
      const uint2 rec = make_uint2(((unsigned)d << 16) | (unsigned)src[e],
                                   __float_as_uint(ew[e]));
      if (pos < BSTRIDE) {
        binbuf[(size_t)bn * BSTRIDE + pos] = rec;
      } else {                       // ~16-sigma event; exact fallback
        int p = atomicAdd(ovfcnt, 1);
        if (p < OVFCAP) ovf[p] = rec;
      }
    }
  } else if (b < nchunk + 1024) {
    const int bid = b - nchunk;
    for (int i = bid * 256 + tid; i < total4; i += 1024 * 256) {
      float4 v = ((const float4*)feat)[i];
      fb[2 * i] = f2bf(v.x) | (f2bf(v.y) << 16);
      fb[2 * i + 1] = f2bf(v.z) | (f2bf(v.w) << 16);
      unsigned q = 0;
      q = __builtin_amdgcn_cvt_pk_fp8_f32(v.x, v.y, q, false);
      q = __builtin_amdgcn_cvt_pk_fp8_f32(v.z, v.w, q, true);
      fbq[i] = q;
    }
  } else {
    const int i = (b - nchunk - 1024) * 256 + tid;
    if (i < 8192) {
      float2 a = ((const float2*)Ws)[i];
      wsb[i] = f2bf(a.x) | (f2bf(a.y) << 16);
      float2 v = ((const float2*)Wn)[i];
      wnb[i] = f2bf(v.x) | (f2bf(v.y) << 16);
    }
  }
}

// ---------------- phase 2: bucket one bin in LDS, dump sequentially --------
__global__ __launch_bounds__(256) void bucket_kernel(
    const int* __restrict__ gbin, const uint2* __restrict__ binbuf,
    int* __restrict__ cnt, unsigned* __restrict__ colw,
    int* __restrict__ ovfcnt, uint2* __restrict__ ovf, int n) {
  __shared__ unsigned lbucket[256 * CAP];   // 32 KB
  __shared__ int lcnt[256];
  const int b = blockIdx.x;
  const int tid = threadIdx.x;
  lcnt[tid] = 0;
  __syncthreads();
  const int lo = b << 8;
  const int m = min(gbin[b], BSTRIDE);
  const uint2* bb = binbuf + (size_t)b * BSTRIDE;
  for (int i = tid; i < m; i += 256) {
    const uint2 rec = bb[i];
    const int dl = (int)(rec.x >> 16) & 255;
    const int r = atomicAdd(&lcnt[dl], 1);       // counts ALL edges -> exact deg
    if (r < CAP) {
      const float w = __uint_as_float(rec.y);
      const unsigned q = (unsigned)(w * 65535.0f + 0.5f);
      lbucket[dl * CAP + r] = ((rec.x & 0xffffu) << 16) | q;
    } else {
      int p = atomicAdd(ovfcnt, 1);
      if (p < OVFCAP) ovf[p] = rec;
    }
  }
  __syncthreads();
  const int nn = min(256, n - lo);
  if (tid < nn) cnt[lo + tid] = lcnt[tid];
  const int tot = nn * CAP;
  unsigned* dstp = colw + (size_t)lo * CAP;
  for (int i = tid; i < tot; i += 256) dstp[i] = lbucket[i];  // sequential
}

// ---------------- gather (fp8): agg[d] = mean_e feat_fp8[src_e]*w_e ---------
// One wave per dst node. Lane = (g, sl): g = edge-parity group (lane>>5),
// sl = channel slot (lane&31) owning channels [4sl, 4sl+4) via one uint
// (4 fp8). Two edges processed per step across the wave; groups summed via
// shfl at the end. Row = 128B -> halves r11's 256B/edge L2/L3 traffic.
__global__ __launch_bounds__(256) void gather_kernel(
    const unsigned* __restrict__ fbq, const int* __restrict__ cnt,
    const unsigned* __restrict__ colw, unsigned* __restrict__ aggu, int n) {
  const int wid = (blockIdx.x * 256 + threadIdx.x) >> 6;
  const int lane = threadIdx.x & 63;
  if (wid >= n) return;
  const int g = lane >> 5;
  const int sl = lane & 31;
  const int dg = cnt[wid];
  const int m = min(dg, CAP);
  const unsigned pv = (lane < m) ? colw[(size_t)wid * CAP + lane] : 0u;
  float a0 = 0.f, a1 = 0.f, a2 = 0.f, a3 = 0.f;
  const float qs = 1.0f / 65535.0f;
  int t = 0;
  for (; t + 8 <= m; t += 8) {     // 8 edges/iter: 4 per group
    unsigned p[4], u[4];
#pragma unroll
    for (int i = 0; i < 4; ++i) p[i] = __shfl(pv, t + 2 * i + g);
#pragma unroll
    for (int i = 0; i < 4; ++i) u[i] = fbq[(size_t)(p[i] >> 16) * 32 + sl];
#pragma unroll
    for (int i = 0; i < 4; ++i) {
      const float w = (float)(p[i] & 0xffffu) * qs;
      a0 += __builtin_amdgcn_cvt_f32_fp8(u[i], 0) * w;
      a1 += __builtin_amdgcn_cvt_f32_fp8(u[i], 1) * w;
      a2 += __builtin_amdgcn_cvt_f32_fp8(u[i], 2) * w;
      a3 += __builtin_amdgcn_cvt_f32_fp8(u[i], 3) * w;
    }
  }
  for (; t + 2 <= m; t += 2) {     // 2 edges/iter
    const unsigned p = __shfl(pv, t + g);
    const unsigned u = fbq[(size_t)(p >> 16) * 32 + sl];
    const float w = (float)(p & 0xffffu) * qs;
    a0 += __builtin_amdgcn_cvt_f32_fp8(u, 0) * w;
    a1 += __builtin_amdgcn_cvt_f32_fp8(u, 1) * w;
    a2 += __builtin_amdgcn_cvt_f32_fp8(u, 2) * w;
    a3 += __builtin_amdgcn_cvt_f32_fp8(u, 3) * w;
  }
  if (t < m && g == 0) {           // odd tail edge: group 0 only
    const unsigned p = __shfl(pv, t);
    const unsigned u = fbq[(size_t)(p >> 16) * 32 + sl];
    const float w = (float)(p & 0xffffu) * qs;
    a0 += __builtin_amdgcn_cvt_f32_fp8(u, 0) * w;
    a1 += __builtin_amdgcn_cvt_f32_fp8(u, 1) * w;
    a2 += __builtin_amdgcn_cvt_f32_fp8(u, 2) * w;
    a3 += __builtin_amdgcn_cvt_f32_fp8(u, 3) * w;
  }
  // combine the two edge-groups: lane<32 adds lane+32's accumulators
  const int peer = (lane + 32) & 63;
  const float b0 = __shfl(a0, peer);
  const float b1 = __shfl(a1, peer);
  const float b2 = __shfl(a2, peer);
  const float b3 = __shfl(a3, peer);
  if (g == 0) {
    const float sc = 1.0f / fmaxf((float)dg, 1.0f);
    const float c0 = (a0 + b0) * sc, c1 = (a1 + b1) * sc;
    const float c2 = (a2 + b2) * sc, c3 = (a3 + b3) * sc;
    uint2 o;
    o.x = f2bf(c0) | (f2bf(c1) << 16);
    o.y = f2bf(c2) | (f2bf(c3) << 16);
    *(uint2*)(aggu + (size_t)wid * 128 + 2 * sl) = o;
  }
}

// ---------------- overflow fallback (exact; expected ~empty) ----------------
__global__ __launch_bounds__(256) void ovf_kernel(
    const unsigned* __restrict__ fb, const int* __restrict__ cnt,
    const int* __restrict__ ovfcnt, const uint2* __restrict__ ovf,
    unsigned* __restrict__ aggu) {
  const int total = min(*ovfcnt, OVFCAP);
  const int nw = (gridDim.x * 256) >> 6;
  const int wid = (blockIdx.x * 256 + threadIdx.x) >> 6;
  const int lane = threadIdx.x & 63;
  for (int i = wid; i < total; i += nw) {
    const uint2 v = ovf[i];
    const int d = (int)(v.x >> 16);
    const int s = (int)(v.x & 0xffffu);
    const float w = __uint_as_float(v.y);
    const float sc = w / fmaxf((float)cnt[d], 1.0f);
    const unsigned u = fb[(size_t)s * 64 + lane];
    const float add0 = __uint_as_float(u << 16) * sc;
    const float add1 = __uint_as_float(u & 0xffff0000u) * sc;
    unsigned* addr = aggu + (size_t)d * 128 + lane;
    unsigned old = *addr, assumed;
    do {
      assumed = old;
      const float x0 = __uint_as_float(assumed << 16) + add0;
      const float x1 = __uint_as_float(assumed & 0xffff0000u) + add1;
      old = atomicCAS(addr, assumed, f2bf(x0) | (f2bf(x1) << 16));
    } while (old != assumed);
  }
}

// ---------------- fused MFMA GEMM (in-place on d_out) ----------------
// out[r] = feat_bf[r] @ Ws_bf.T + b + agg_bf[r] @ Wn_bf.T
__global__ __launch_bounds__(256) void fused_gemm_kernel(
    const ushort* __restrict__ fb,     // feat bf16 [n][128]
    const unsigned* __restrict__ aggu, // agg bf16 packed, row stride 128 uints
    const ushort* __restrict__ wsb,    // Ws bf16 [128][128]
    const ushort* __restrict__ wnb,    // Wn bf16 [128][128]
    const float* __restrict__ bsv,     // bias [128]
    float* __restrict__ out,           // final f32 (same buffer as aggu)
    int n) {
  const int lane = threadIdx.x & 63;
  const int wid = (blockIdx.x * 256 + threadIdx.x) >> 6;
  const int row0 = wid * 16;
  if (row0 >= n) return;
  const int rlo = lane & 15;
  const int g = lane >> 4;

  f32x4 acc[8];
#pragma unroll
  for (int ct = 0; ct < 8; ++ct) {
    float bv = bsv[ct * 16 + rlo];
    acc[ct] = (f32x4){bv, bv, bv, bv};
  }

  const int rowA = min(row0 + rlo, n - 1);   // clamp stays inside last strip

#pragma unroll
  for (int kc = 0; kc < 4; ++kc) {
    const int k0 = kc * 32 + g * 8;
    const bf16x8 aself = *(const bf16x8*)(fb + (size_t)rowA * 128 + k0);
    const bf16x8 aagg = *(const bf16x8*)(aggu + (size_t)rowA * 128 + (k0 >> 1));
#pragma unroll
    for (int ct = 0; ct < 8; ++ct) {
      const int c = ct * 16 + rlo;
      const bf16x8 bsw = *(const bf16x8*)(wsb + (size_t)c * 128 + k0);
      const bf16x8 bnw = *(const bf16x8*)(wnb + (size_t)c * 128 + k0);
      acc[ct] = __builtin_amdgcn_mfma_f32_16x16x32_bf16(aself, bsw, acc[ct], 0, 0, 0);
      acc[ct] = __builtin_amdgcn_mfma_f32_16x16x32_bf16(aagg, bnw, acc[ct], 0, 0, 0);
    }
  }

  // C/D layout: col = ct*16 + (lane&15), row = (lane>>4)*4 + j   [m89-verified]
#pragma unroll
  for (int ct = 0; ct < 8; ++ct) {
#pragma unroll
    for (int j = 0; j < 4; ++j) {
      const int r = row0 + g * 4 + j;
      if (r < n) out[(size_t)r * 128 + ct * 16 + rlo] = acc[ct][j];
    }
  }
}

extern "C" void kernel_launch(void* const* d_in, const int* in_sizes, int n_in,
                              void* d_out, int out_size, void* d_ws, size_t ws_size,
                              hipStream_t stream) {
  const float* feat = (const float*)d_in[0];
  const int* src = (const int*)d_in[1];
  const int* dst = (const int*)d_in[2];
  const float* ew = (const float*)d_in[3];
  const float* Wn = (const float*)d_in[4];
  const float* Ws = (const float*)d_in[5];
  const float* bs = (const float*)d_in[6];
  const int n = in_sizes[0] / 128;
  const int E = in_sizes[1];
  float* out = (float*)d_out;
  unsigned* aggu = (unsigned*)d_out;

  const int nbins = (n + 255) >> 8;

  // ws: colw 6.4 | cnt ~0.2 | ovf 0.5 | binbuf 8 | fb 12.8 | fbq 6.4 | W 0.06
  // ≈ 34.4MB (ws_size >= 256MB per harness fills observed r10/r11).
  char* w = (char*)d_ws;
  size_t off_colw = 0;
  size_t off_cnt = (off_colw + (size_t)n * CAP * 4 + 255) & ~(size_t)255;
  size_t off_ovf = (off_cnt + (size_t)(n + 1 + 256) * 4 + 255) & ~(size_t)255;
  size_t off_binbuf = (off_ovf + (size_t)OVFCAP * 8 + 255) & ~(size_t)255;
  size_t off_fb = (off_binbuf + (size_t)256 * BSTRIDE * 8 + 255) & ~(size_t)255;
  size_t off_fbq = (off_fb + (size_t)n * 64 * 4 + 255) & ~(size_t)255;
  size_t off_wsb = (off_fbq + (size_t)n * 32 * 4 + 255) & ~(size_t)255;
  size_t off_wnb = off_wsb + 8192 * 4;
  unsigned* colw = (unsigned*)(w + off_colw);
  int* cnt = (int*)(w + off_cnt);
  int* ovfcnt = cnt + n;
  int* gbin = cnt + n + 1;                  // 256 ints
  uint2* ovf = (uint2*)(w + off_ovf);
  uint2* binbuf = (uint2*)(w + off_binbuf);
  unsigned* fb = (unsigned*)(w + off_fb);
  unsigned* fbq = (unsigned*)(w + off_fbq);
  unsigned* wsb = (unsigned*)(w + off_wsb);
  unsigned* wnb = (unsigned*)(w + off_wnb);

  zero_kernel<<<1, 512, 0, stream>>>(ovfcnt);   // ovfcnt + gbin (257 ints)

  const int nchunk = (E + BINCHUNK - 1) / BINCHUNK;
  prep_kernel<<<nchunk + 1024 + 32, 256, 0, stream>>>(
      src, dst, ew, gbin, binbuf, ovfcnt, ovf, E,
      feat, fb, fbq, n * 32, Ws, Wn, wsb, wnb, nchunk);

  bucket_kernel<<<nbins, 256, 0, stream>>>(gbin, binbuf, cnt, colw, ovfcnt, ovf, n);

  // agg (packed bf16) -> d_out rows
  gather_kernel<<<(n * 64 + 255) / 256, 256, 0, stream>>>(fbq, cnt, colw, aggu, n);
  ovf_kernel<<<32, 256, 0, stream>>>(fb, cnt, ovfcnt, ovf, aggu);

  // fused: out = feat@Ws.T + b + agg@Wn.T   (in-place on d_out)
  const int nstrips = (n + 15) / 16;
  fused_gemm_kernel<<<(nstrips + 3) / 4, 256, 0, stream>>>(
      (const ushort*)fb, aggu, (const ushort*)wsb, (const ushort*)wnb, bs, out, n);
}

// Round 13
// 100.092 us; speedup vs baseline: 2.3290x; 1.0096x over previous
//
#include <hip/hip_runtime.h>

#define CAP 32        // per-node bucket capacity (mean deg 16; overflow handled exactly)
#define OVFCAP 65536
#define BSTRIDE 5120  // records per bin (mean 4096, +16 sigma)
#define BINCHUNK 4096 // edges per bin-phase block

typedef __attribute__((ext_vector_type(8))) short bf16x8;
typedef __attribute__((ext_vector_type(4))) float f32x4;

__device__ __forceinline__ unsigned f2bf(float x) {
  unsigned u = __float_as_uint(x);
  return (u + 0x7fffu + ((u >> 16) & 1u)) >> 16;   // RN-even
}

// ---------------- zero: ovfcnt (1) + gbin (256) ----------------
__global__ __launch_bounds__(512) void zero_kernel(int* __restrict__ p) {
  if (threadIdx.x < 257) p[threadIdx.x] = 0;
}

// ---------------- prep: bin | feat->bf16+fp8 | W->bf16, one launch ---------
// Blocks [0,nchunk): partition edges into 256-node dst bins.
// Blocks [nchunk, nchunk+1024): cvt feat to packed bf16 (fb) AND fp8 (fbq).
// Last 32 blocks: convert Ws/Wn.
__global__ __launch_bounds__(256) void prep_kernel(
    const int* __restrict__ src, const int* __restrict__ dst,
    const float* __restrict__ ew, int* __restrict__ gbin,
    uint2* __restrict__ binbuf, int* __restrict__ ovfcnt,
    uint2* __restrict__ ovf, int E,
    const float* __restrict__ feat, unsigned* __restrict__ fb,
    unsigned* __restrict__ fbq, int total4,
    const float* __restrict__ Ws, const float* __restrict__ Wn,
    unsigned* __restrict__ wsb, unsigned* __restrict__ wnb,
    int nchunk) {
  __shared__ int lcnt[256];
  __shared__ int lbase[256];
  const int b = blockIdx.x;
  const int tid = threadIdx.x;
  if (b < nchunk) {
    lcnt[tid] = 0;
    __syncthreads();
    const int e0 = b * BINCHUNK;
    const int e1 = min(E, e0 + BINCHUNK);
    int dreg[BINCHUNK / 256];          // static-indexed -> stays in VGPRs
#pragma unroll
    for (int i = 0; i < BINCHUNK / 256; ++i) {
      const int e = e0 + i * 256 + tid;
      dreg[i] = (e < e1) ? dst[e] : -1;
      if (dreg[i] >= 0) atomicAdd(&lcnt[dreg[i] >> 8], 1);
    }
    __syncthreads();
    lbase[tid] = lcnt[tid] ? atomicAdd(&gbin[tid], lcnt[tid]) : 0;
    lcnt[tid] = 0;
    __syncthreads();
#pragma unroll
    for (int i = 0; i < BINCHUNK / 256; ++i) {
      const int e = e0 + i * 256 + tid;
      if (e < e1) {
        const int d = dreg[i];
        const int bn = d >> 8;
        const int r = atomicAdd(&lcnt[bn], 1);
        const int pos = lbase[bn] + r;
        const uint2 rec = make_uint2(((unsigned)d << 16) | (unsigned)src[e],
                                     __float_as_uint(ew[e]));
        if (pos < BSTRIDE) {
          binbuf[(size_t)bn * BSTRIDE + pos] = rec;
        } else {                       // ~16-sigma event; exact fallback
          int p = atomicAdd(ovfcnt, 1);
          if (p < OVFCAP) ovf[p] = rec;
        }
      }
    }
  } else if (b < nchunk + 1024) {
    const int bid = b - nchunk;
    for (int i = bid * 256 + tid; i < total4; i += 1024 * 256) {
      float4 v = ((const float4*)feat)[i];
      fb[2 * i] = f2bf(v.x) | (f2bf(v.y) << 16);
      fb[2 * i + 1] = f2bf(v.z) | (f2bf(v.w) << 16);
      unsigned q = 0;
      q = __builtin_amdgcn_cvt_pk_fp8_f32(v.x, v.y, q, false);
      q = __builtin_amdgcn_cvt_pk_fp8_f32(v.z, v.w, q, true);
      fbq[i] = q;
    }
  } else {
    const int i = (b - nchunk - 1024) * 256 + tid;
    if (i < 8192) {
      float2 a = ((const float2*)Ws)[i];
      wsb[i] = f2bf(a.x) | (f2bf(a.y) << 16);
      float2 v = ((const float2*)Wn)[i];
      wnb[i] = f2bf(v.x) | (f2bf(v.y) << 16);
    }
  }
}

// ---------------- phase 2: bucket one bin in LDS, dump sequentially --------
__global__ __launch_bounds__(256) void bucket_kernel(
    const int* __restrict__ gbin, const uint2* __restrict__ binbuf,
    int* __restrict__ cnt, unsigned* __restrict__ colw,
    int* __restrict__ ovfcnt, uint2* __restrict__ ovf, int n) {
  __shared__ uint4 lbucket4[256 * CAP / 4];   // 32 KB
  __shared__ int lcnt[256];
  unsigned* lbucket = (unsigned*)lbucket4;
  const int b = blockIdx.x;
  const int tid = threadIdx.x;
  lcnt[tid] = 0;
  __syncthreads();
  const int lo = b << 8;
  const int m = min(gbin[b], BSTRIDE);
  const uint2* bb = binbuf + (size_t)b * BSTRIDE;
  for (int i = tid; i < m; i += 256) {
    const uint2 rec = bb[i];
    const int dl = (int)(rec.x >> 16) & 255;
    const int r = atomicAdd(&lcnt[dl], 1);       // counts ALL edges -> exact deg
    if (r < CAP) {
      const float w = __uint_as_float(rec.y);
      const unsigned q = (unsigned)(w * 65535.0f + 0.5f);
      lbucket[dl * CAP + r] = ((rec.x & 0xffffu) << 16) | q;
    } else {
      int p = atomicAdd(ovfcnt, 1);
      if (p < OVFCAP) ovf[p] = rec;
    }
  }
  __syncthreads();
  const int nn = min(256, n - lo);
  if (tid < nn) cnt[lo + tid] = lcnt[tid];
  const int tot4 = (nn * CAP) >> 2;            // CAP=32 -> multiple of 4
  uint4* d4 = (uint4*)(colw + (size_t)lo * CAP);
  for (int i = tid; i < tot4; i += 256) d4[i] = lbucket4[i];  // sequential 16B
}

// ---------------- gather (fp8) + inline overflow -----------------------------
// One wave per dst node. Lane = (g, sl): g = edge-parity group (lane>>5),
// sl = channel slot (lane&31) owning channels [4sl,4sl+4) via one uint.
// 16-wide main loop: 8 independent fbq loads per group in flight.
// Overflow entries (expected none) folded in before the mean-divide:
// adding w*feat then dividing by deg == old post-pass (w/deg)*feat CAS.
__global__ __launch_bounds__(256) void gather_kernel(
    const unsigned* __restrict__ fbq, const int* __restrict__ cnt,
    const unsigned* __restrict__ colw, const int* __restrict__ ovfcnt,
    const uint2* __restrict__ ovf, unsigned* __restrict__ aggu, int n) {
  const int wid = (blockIdx.x * 256 + threadIdx.x) >> 6;
  const int lane = threadIdx.x & 63;
  if (wid >= n) return;
  const int g = lane >> 5;
  const int sl = lane & 31;
  const int dg = cnt[wid];
  const int m = min(dg, CAP);
  const unsigned pv = (lane < m) ? colw[(size_t)wid * CAP + lane] : 0u;
  float a0 = 0.f, a1 = 0.f, a2 = 0.f, a3 = 0.f;
  const float qs = 1.0f / 65535.0f;
  int t = 0;
  for (; t + 16 <= m; t += 16) {   // 16 edges/iter: 8 per group
    unsigned p[8], u[8];
#pragma unroll
    for (int i = 0; i < 8; ++i) p[i] = __shfl(pv, t + 2 * i + g);
#pragma unroll
    for (int i = 0; i < 8; ++i) u[i] = fbq[(size_t)(p[i] >> 16) * 32 + sl];
#pragma unroll
    for (int i = 0; i < 8; ++i) {
      const float w = (float)(p[i] & 0xffffu) * qs;
      a0 += __builtin_amdgcn_cvt_f32_fp8(u[i], 0) * w;
      a1 += __builtin_amdgcn_cvt_f32_fp8(u[i], 1) * w;
      a2 += __builtin_amdgcn_cvt_f32_fp8(u[i], 2) * w;
      a3 += __builtin_amdgcn_cvt_f32_fp8(u[i], 3) * w;
    }
  }
  if (t + 8 <= m) {                // 8 edges: 4 per group
    unsigned p[4], u[4];
#pragma unroll
    for (int i = 0; i < 4; ++i) p[i] = __shfl(pv, t + 2 * i + g);
#pragma unroll
    for (int i = 0; i < 4; ++i) u[i] = fbq[(size_t)(p[i] >> 16) * 32 + sl];
#pragma unroll
    for (int i = 0; i < 4; ++i) {
      const float w = (float)(p[i] & 0xffffu) * qs;
      a0 += __builtin_amdgcn_cvt_f32_fp8(u[i], 0) * w;
      a1 += __builtin_amdgcn_cvt_f32_fp8(u[i], 1) * w;
      a2 += __builtin_amdgcn_cvt_f32_fp8(u[i], 2) * w;
      a3 += __builtin_amdgcn_cvt_f32_fp8(u[i], 3) * w;
    }
    t += 8;
  }
  for (; t + 2 <= m; t += 2) {     // 2 edges/iter
    const unsigned p = __shfl(pv, t + g);
    const unsigned u = fbq[(size_t)(p >> 16) * 32 + sl];
    const float w = (float)(p & 0xffffu) * qs;
    a0 += __builtin_amdgcn_cvt_f32_fp8(u, 0) * w;
    a1 += __builtin_amdgcn_cvt_f32_fp8(u, 1) * w;
    a2 += __builtin_amdgcn_cvt_f32_fp8(u, 2) * w;
    a3 += __builtin_amdgcn_cvt_f32_fp8(u, 3) * w;
  }
  if (t < m && g == 0) {           // odd tail edge: group 0 only
    const unsigned p = __shfl(pv, t);
    const unsigned u = fbq[(size_t)(p >> 16) * 32 + sl];
    const float w = (float)(p & 0xffffu) * qs;
    a0 += __builtin_amdgcn_cvt_f32_fp8(u, 0) * w;
    a1 += __builtin_amdgcn_cvt_f32_fp8(u, 1) * w;
    a2 += __builtin_amdgcn_cvt_f32_fp8(u, 2) * w;
    a3 += __builtin_amdgcn_cvt_f32_fp8(u, 3) * w;
  }
  // inline overflow (deg>CAP nodes / bin spill); expected empty
  const int novf = min(*ovfcnt, OVFCAP);
  if (novf > 0 && g == 0) {
    for (int i = 0; i < novf; ++i) {
      const uint2 v = ovf[i];
      if ((int)(v.x >> 16) == wid) {
        const unsigned u = fbq[(size_t)(v.x & 0xffffu) * 32 + sl];
        const float w = __uint_as_float(v.y);
        a0 += __builtin_amdgcn_cvt_f32_fp8(u, 0) * w;
        a1 += __builtin_amdgcn_cvt_f32_fp8(u, 1) * w;
        a2 += __builtin_amdgcn_cvt_f32_fp8(u, 2) * w;
        a3 += __builtin_amdgcn_cvt_f32_fp8(u, 3) * w;
      }
    }
  }
  // combine the two edge-groups: lane<32 adds lane+32's accumulators
  const int peer = (lane + 32) & 63;
  const float b0 = __shfl(a0, peer);
  const float b1 = __shfl(a1, peer);
  const float b2 = __shfl(a2, peer);
  const float b3 = __shfl(a3, peer);
  if (g == 0) {
    const float sc = 1.0f / fmaxf((float)dg, 1.0f);
    const float c0 = (a0 + b0) * sc, c1 = (a1 + b1) * sc;
    const float c2 = (a2 + b2) * sc, c3 = (a3 + b3) * sc;
    uint2 o;
    o.x = f2bf(c0) | (f2bf(c1) << 16);
    o.y = f2bf(c2) | (f2bf(c3) << 16);
    *(uint2*)(aggu + (size_t)wid * 128 + 2 * sl) = o;
  }
}

// ---------------- fused MFMA GEMM (in-place on d_out) ----------------
// out[r] = feat_bf[r] @ Ws_bf.T + b + agg_bf[r] @ Wn_bf.T
__global__ __launch_bounds__(256) void fused_gemm_kernel(
    const ushort* __restrict__ fb,     // feat bf16 [n][128]
    const unsigned* __restrict__ aggu, // agg bf16 packed, row stride 128 uints
    const ushort* __restrict__ wsb,    // Ws bf16 [128][128]
    const ushort* __restrict__ wnb,    // Wn bf16 [128][128]
    const float* __restrict__ bsv,     // bias [128]
    float* __restrict__ out,           // final f32 (same buffer as aggu)
    int n) {
  const int lane = threadIdx.x & 63;
  const int wid = (blockIdx.x * 256 + threadIdx.x) >> 6;
  const int row0 = wid * 16;
  if (row0 >= n) return;
  const int rlo = lane & 15;
  const int g = lane >> 4;

  f32x4 acc[8];
#pragma unroll
  for (int ct = 0; ct < 8; ++ct) {
    float bv = bsv[ct * 16 + rlo];
    acc[ct] = (f32x4){bv, bv, bv, bv};
  }

  const int rowA = min(row0 + rlo, n - 1);   // clamp stays inside last strip

#pragma unroll
  for (int kc = 0; kc < 4; ++kc) {
    const int k0 = kc * 32 + g * 8;
    const bf16x8 aself = *(const bf16x8*)(fb + (size_t)rowA * 128 + k0);
    const bf16x8 aagg = *(const bf16x8*)(aggu + (size_t)rowA * 128 + (k0 >> 1));
#pragma unroll
    for (int ct = 0; ct < 8; ++ct) {
      const int c = ct * 16 + rlo;
      const bf16x8 bsw = *(const bf16x8*)(wsb + (size_t)c * 128 + k0);
      const bf16x8 bnw = *(const bf16x8*)(wnb + (size_t)c * 128 + k0);
      acc[ct] = __builtin_amdgcn_mfma_f32_16x16x32_bf16(aself, bsw, acc[ct], 0, 0, 0);
      acc[ct] = __builtin_amdgcn_mfma_f32_16x16x32_bf16(aagg, bnw, acc[ct], 0, 0, 0);
    }
  }

  // C/D layout: col = ct*16 + (lane&15), row = (lane>>4)*4 + j   [m89-verified]
#pragma unroll
  for (int ct = 0; ct < 8; ++ct) {
#pragma unroll
    for (int j = 0; j < 4; ++j) {
      const int r = row0 + g * 4 + j;
      if (r < n) out[(size_t)r * 128 + ct * 16 + rlo] = acc[ct][j];
    }
  }
}

extern "C" void kernel_launch(void* const* d_in, const int* in_sizes, int n_in,
                              void* d_out, int out_size, void* d_ws, size_t ws_size,
                              hipStream_t stream) {
  const float* feat = (const float*)d_in[0];
  const int* src = (const int*)d_in[1];
  const int* dst = (const int*)d_in[2];
  const float* ew = (const float*)d_in[3];
  const float* Wn = (const float*)d_in[4];
  const float* Ws = (const float*)d_in[5];
  const float* bs = (const float*)d_in[6];
  const int n = in_sizes[0] / 128;
  const int E = in_sizes[1];
  float* out = (float*)d_out;
  unsigned* aggu = (unsigned*)d_out;

  const int nbins = (n + 255) >> 8;

  // ws: colw 6.4 | cnt ~0.2 | ovf 0.5 | binbuf 8 | fb 12.8 | fbq 6.4 | W 0.06
  char* w = (char*)d_ws;
  size_t off_colw = 0;
  size_t off_cnt = (off_colw + (size_t)n * CAP * 4 + 255) & ~(size_t)255;
  size_t off_ovf = (off_cnt + (size_t)(n + 1 + 256) * 4 + 255) & ~(size_t)255;
  size_t off_binbuf = (off_ovf + (size_t)OVFCAP * 8 + 255) & ~(size_t)255;
  size_t off_fb = (off_binbuf + (size_t)256 * BSTRIDE * 8 + 255) & ~(size_t)255;
  size_t off_fbq = (off_fb + (size_t)n * 64 * 4 + 255) & ~(size_t)255;
  size_t off_wsb = (off_fbq + (size_t)n * 32 * 4 + 255) & ~(size_t)255;
  size_t off_wnb = off_wsb + 8192 * 4;
  unsigned* colw = (unsigned*)(w + off_colw);
  int* cnt = (int*)(w + off_cnt);
  int* ovfcnt = cnt + n;
  int* gbin = cnt + n + 1;                  // 256 ints
  uint2* ovf = (uint2*)(w + off_ovf);
  uint2* binbuf = (uint2*)(w + off_binbuf);
  unsigned* fb = (unsigned*)(w + off_fb);
  unsigned* fbq = (unsigned*)(w + off_fbq);
  unsigned* wsb = (unsigned*)(w + off_wsb);
  unsigned* wnb = (unsigned*)(w + off_wnb);

  zero_kernel<<<1, 512, 0, stream>>>(ovfcnt);   // ovfcnt + gbin (257 ints)

  const int nchunk = (E + BINCHUNK - 1) / BINCHUNK;
  prep_kernel<<<nchunk + 1024 + 32, 256, 0, stream>>>(
      src, dst, ew, gbin, binbuf, ovfcnt, ovf, E,
      feat, fb, fbq, n * 32, Ws, Wn, wsb, wnb, nchunk);

  bucket_kernel<<<nbins, 256, 0, stream>>>(gbin, binbuf, cnt, colw, ovfcnt, ovf, n);

  // agg (packed bf16) -> d_out rows; overflow folded in
  gather_kernel<<<(n * 64 + 255) / 256, 256, 0, stream>>>(
      fbq, cnt, colw, ovfcnt, ovf, aggu, n);

  // fused: out = feat@Ws.T + b + agg@Wn.T   (in-place on d_out)
  const int nstrips = (n + 15) / 16;
  fused_gemm_kernel<<<(nstrips + 3) / 4, 256, 0, stream>>>(
      (const ushort*)fb, aggu, (const ushort*)wsb, (const ushort*)wnb, bs, out, n);
}

// Round 14
// 75.623 us; speedup vs baseline: 3.0826x; 1.3236x over previous
//
#include <hip/hip_runtime.h>

#define CAP 32        // per-node bucket capacity (mean deg 16; overflow handled exactly)
#define OVFCAP 65536
#define BSTRIDE 5120  // records per bin (mean 4096, +16 sigma)
#define BINCHUNK 4096 // edges per bin-phase block

typedef __attribute__((ext_vector_type(8))) short bf16x8;
typedef __attribute__((ext_vector_type(4))) float f32x4;

__device__ __forceinline__ unsigned f2bf(float x) {
  unsigned u = __float_as_uint(x);
  return (u + 0x7fffu + ((u >> 16) & 1u)) >> 16;   // RN-even
}

__device__ __forceinline__ bf16x8 u4_to_bf(uint4 v) {
  union { uint4 u; bf16x8 b; } cv;
  cv.u = v;
  return cv.b;
}

// ---------------- zero: ovfcnt (1) + gbin (256) ----------------
__global__ __launch_bounds__(512) void zero_kernel(int* __restrict__ p) {
  if (threadIdx.x < 257) p[threadIdx.x] = 0;
}

// ---------------- prep: bin | feat->bf16+fp8 | W->bf16, one launch ---------
__global__ __launch_bounds__(256) void prep_kernel(
    const int* __restrict__ src, const int* __restrict__ dst,
    const float* __restrict__ ew, int* __restrict__ gbin,
    uint2* __restrict__ binbuf, int* __restrict__ ovfcnt,
    uint2* __restrict__ ovf, int E,
    const float* __restrict__ feat, unsigned* __restrict__ fb,
    unsigned* __restrict__ fbq, int total4,
    const float* __restrict__ Ws, const float* __restrict__ Wn,
    unsigned* __restrict__ wsb, unsigned* __restrict__ wnb,
    int nchunk) {
  __shared__ int lcnt[256];
  __shared__ int lbase[256];
  const int b = blockIdx.x;
  const int tid = threadIdx.x;
  if (b < nchunk) {
    lcnt[tid] = 0;
    __syncthreads();
    const int e0 = b * BINCHUNK;
    const int e1 = min(E, e0 + BINCHUNK);
    int dreg[BINCHUNK / 256];          // static-indexed -> stays in VGPRs
#pragma unroll
    for (int i = 0; i < BINCHUNK / 256; ++i) {
      const int e = e0 + i * 256 + tid;
      dreg[i] = (e < e1) ? dst[e] : -1;
      if (dreg[i] >= 0) atomicAdd(&lcnt[dreg[i] >> 8], 1);
    }
    __syncthreads();
    lbase[tid] = lcnt[tid] ? atomicAdd(&gbin[tid], lcnt[tid]) : 0;
    lcnt[tid] = 0;
    __syncthreads();
#pragma unroll
    for (int i = 0; i < BINCHUNK / 256; ++i) {
      const int e = e0 + i * 256 + tid;
      if (e < e1) {
        const int d = dreg[i];
        const int bn = d >> 8;
        const int r = atomicAdd(&lcnt[bn], 1);
        const int pos = lbase[bn] + r;
        const uint2 rec = make_uint2(((unsigned)d << 16) | (unsigned)src[e],
                                     __float_as_uint(ew[e]));
        if (pos < BSTRIDE) {
          binbuf[(size_t)bn * BSTRIDE + pos] = rec;
        } else {                       // ~16-sigma event; exact fallback
          int p = atomicAdd(ovfcnt, 1);
          if (p < OVFCAP) ovf[p] = rec;
        }
      }
    }
  } else if (b < nchunk + 1024) {
    const int bid = b - nchunk;
    for (int i = bid * 256 + tid; i < total4; i += 1024 * 256) {
      float4 v = ((const float4*)feat)[i];
      fb[2 * i] = f2bf(v.x) | (f2bf(v.y) << 16);
      fb[2 * i + 1] = f2bf(v.z) | (f2bf(v.w) << 16);
      unsigned q = 0;
      q = __builtin_amdgcn_cvt_pk_fp8_f32(v.x, v.y, q, false);
      q = __builtin_amdgcn_cvt_pk_fp8_f32(v.z, v.w, q, true);
      fbq[i] = q;
    }
  } else {
    const int i = (b - nchunk - 1024) * 256 + tid;
    if (i < 8192) {
      float2 a = ((const float2*)Ws)[i];
      wsb[i] = f2bf(a.x) | (f2bf(a.y) << 16);
      float2 v = ((const float2*)Wn)[i];
      wnb[i] = f2bf(v.x) | (f2bf(v.y) << 16);
    }
  }
}

// ---------------- phase 2: bucket one bin in LDS, dump sequentially --------
__global__ __launch_bounds__(256) void bucket_kernel(
    const int* __restrict__ gbin, const uint2* __restrict__ binbuf,
    int* __restrict__ cnt, unsigned* __restrict__ colw,
    int* __restrict__ ovfcnt, uint2* __restrict__ ovf, int n) {
  __shared__ uint4 lbucket4[256 * CAP / 4];   // 32 KB
  __shared__ int lcnt[256];
  unsigned* lbucket = (unsigned*)lbucket4;
  const int b = blockIdx.x;
  const int tid = threadIdx.x;
  lcnt[tid] = 0;
  __syncthreads();
  const int lo = b << 8;
  const int m = min(gbin[b], BSTRIDE);
  const uint2* bb = binbuf + (size_t)b * BSTRIDE;
  for (int i = tid; i < m; i += 256) {
    const uint2 rec = bb[i];
    const int dl = (int)(rec.x >> 16) & 255;
    const int r = atomicAdd(&lcnt[dl], 1);       // counts ALL edges -> exact deg
    if (r < CAP) {
      const float w = __uint_as_float(rec.y);
      const unsigned q = (unsigned)(w * 65535.0f + 0.5f);
      lbucket[dl * CAP + r] = ((rec.x & 0xffffu) << 16) | q;
    } else {
      int p = atomicAdd(ovfcnt, 1);
      if (p < OVFCAP) ovf[p] = rec;
    }
  }
  __syncthreads();
  const int nn = min(256, n - lo);
  if (tid < nn) cnt[lo + tid] = lcnt[tid];
  const int tot4 = (nn * CAP) >> 2;            // CAP=32 -> multiple of 4
  uint4* d4 = (uint4*)(colw + (size_t)lo * CAP);
  for (int i = tid; i < tot4; i += 256) d4[i] = lbucket4[i];  // sequential 16B
}

// ---------------- gather (fp8) + inline overflow -----------------------------
__global__ __launch_bounds__(256) void gather_kernel(
    const unsigned* __restrict__ fbq, const int* __restrict__ cnt,
    const unsigned* __restrict__ colw, const int* __restrict__ ovfcnt,
    const uint2* __restrict__ ovf, unsigned* __restrict__ aggu, int n) {
  const int wid = (blockIdx.x * 256 + threadIdx.x) >> 6;
  const int lane = threadIdx.x & 63;
  if (wid >= n) return;
  const int g = lane >> 5;
  const int sl = lane & 31;
  const int dg = cnt[wid];
  const int m = min(dg, CAP);
  const unsigned pv = (lane < m) ? colw[(size_t)wid * CAP + lane] : 0u;
  float a0 = 0.f, a1 = 0.f, a2 = 0.f, a3 = 0.f;
  const float qs = 1.0f / 65535.0f;
  int t = 0;
  for (; t + 16 <= m; t += 16) {   // 16 edges/iter: 8 per group
    unsigned p[8], u[8];
#pragma unroll
    for (int i = 0; i < 8; ++i) p[i] = __shfl(pv, t + 2 * i + g);
#pragma unroll
    for (int i = 0; i < 8; ++i) u[i] = fbq[(size_t)(p[i] >> 16) * 32 + sl];
#pragma unroll
    for (int i = 0; i < 8; ++i) {
      const float w = (float)(p[i] & 0xffffu) * qs;
      a0 += __builtin_amdgcn_cvt_f32_fp8(u[i], 0) * w;
      a1 += __builtin_amdgcn_cvt_f32_fp8(u[i], 1) * w;
      a2 += __builtin_amdgcn_cvt_f32_fp8(u[i], 2) * w;
      a3 += __builtin_amdgcn_cvt_f32_fp8(u[i], 3) * w;
    }
  }
  if (t + 8 <= m) {                // 8 edges: 4 per group
    unsigned p[4], u[4];
#pragma unroll
    for (int i = 0; i < 4; ++i) p[i] = __shfl(pv, t + 2 * i + g);
#pragma unroll
    for (int i = 0; i < 4; ++i) u[i] = fbq[(size_t)(p[i] >> 16) * 32 + sl];
#pragma unroll
    for (int i = 0; i < 4; ++i) {
      const float w = (float)(p[i] & 0xffffu) * qs;
      a0 += __builtin_amdgcn_cvt_f32_fp8(u[i], 0) * w;
      a1 += __builtin_amdgcn_cvt_f32_fp8(u[i], 1) * w;
      a2 += __builtin_amdgcn_cvt_f32_fp8(u[i], 2) * w;
      a3 += __builtin_amdgcn_cvt_f32_fp8(u[i], 3) * w;
    }
    t += 8;
  }
  for (; t + 2 <= m; t += 2) {     // 2 edges/iter
    const unsigned p = __shfl(pv, t + g);
    const unsigned u = fbq[(size_t)(p >> 16) * 32 + sl];
    const float w = (float)(p & 0xffffu) * qs;
    a0 += __builtin_amdgcn_cvt_f32_fp8(u, 0) * w;
    a1 += __builtin_amdgcn_cvt_f32_fp8(u, 1) * w;
    a2 += __builtin_amdgcn_cvt_f32_fp8(u, 2) * w;
    a3 += __builtin_amdgcn_cvt_f32_fp8(u, 3) * w;
  }
  if (t < m && g == 0) {           // odd tail edge: group 0 only
    const unsigned p = __shfl(pv, t);
    const unsigned u = fbq[(size_t)(p >> 16) * 32 + sl];
    const float w = (float)(p & 0xffffu) * qs;
    a0 += __builtin_amdgcn_cvt_f32_fp8(u, 0) * w;
    a1 += __builtin_amdgcn_cvt_f32_fp8(u, 1) * w;
    a2 += __builtin_amdgcn_cvt_f32_fp8(u, 2) * w;
    a3 += __builtin_amdgcn_cvt_f32_fp8(u, 3) * w;
  }
  // inline overflow (deg>CAP nodes / bin spill); expected empty
  const int novf = min(*ovfcnt, OVFCAP);
  if (novf > 0 && g == 0) {
    for (int i = 0; i < novf; ++i) {
      const uint2 v = ovf[i];
      if ((int)(v.x >> 16) == wid) {
        const unsigned u = fbq[(size_t)(v.x & 0xffffu) * 32 + sl];
        const float w = __uint_as_float(v.y);
        a0 += __builtin_amdgcn_cvt_f32_fp8(u, 0) * w;
        a1 += __builtin_amdgcn_cvt_f32_fp8(u, 1) * w;
        a2 += __builtin_amdgcn_cvt_f32_fp8(u, 2) * w;
        a3 += __builtin_amdgcn_cvt_f32_fp8(u, 3) * w;
      }
    }
  }
  // combine the two edge-groups: lane<32 adds lane+32's accumulators
  const int peer = (lane + 32) & 63;
  const float b0 = __shfl(a0, peer);
  const float b1 = __shfl(a1, peer);
  const float b2 = __shfl(a2, peer);
  const float b3 = __shfl(a3, peer);
  if (g == 0) {
    const float sc = 1.0f / fmaxf((float)dg, 1.0f);
    const float c0 = (a0 + b0) * sc, c1 = (a1 + b1) * sc;
    const float c2 = (a2 + b2) * sc, c3 = (a3 + b3) * sc;
    uint2 o;
    o.x = f2bf(c0) | (f2bf(c1) << 16);
    o.y = f2bf(c2) | (f2bf(c3) << 16);
    *(uint2*)(aggu + (size_t)wid * 128 + 2 * sl) = o;
  }
}

// ---------------- fused MFMA GEMM, LDS-staged W (in-place on d_out) ---------
// out[r] = feat_bf[r] @ Ws_bf.T + b + agg_bf[r] @ Wn_bf.T
// Block = 4 waves x 32 rows = 128 rows. Ws|Wn staged in LDS as
// [128 rows][32 slots of 16B], slot-swizzled s^(c&7) (2-way conflicts = free).
// Each wave: 2 row-tiles share every B fragment -> MFMA:ds_read = 2:1.
// r13 profile: per-wave L2 W re-reads made this kernel 40us, MfmaUtil ~3%.
__global__ __launch_bounds__(256) void fused_gemm_kernel(
    const ushort* __restrict__ fb,     // feat bf16 [n][128]
    const unsigned* __restrict__ aggu, // agg bf16 packed, row stride 128 uints
    const uint4* __restrict__ ws4,     // Ws bf16 [128][16 x 16B]
    const uint4* __restrict__ wn4,     // Wn bf16 [128][16 x 16B]
    const float* __restrict__ bsv,     // bias [128]
    float* __restrict__ out,           // final f32 (same buffer as aggu)
    int n) {
  __shared__ uint4 wlds[128 * 32];     // 64 KB
  const int tid = threadIdx.x;
  for (int i = tid; i < 2048; i += 256) {
    const int c = i >> 4, s = i & 15;
    const int sw = s ^ (c & 7);
    wlds[c * 32 + sw] = ws4[i];
    wlds[c * 32 + 16 + sw] = wn4[i];
  }
  __syncthreads();

  const int lane = tid & 63;
  const int wv = tid >> 6;
  const int row0 = (blockIdx.x * 4 + wv) * 32;
  if (row0 >= n) return;
  const int rlo = lane & 15;
  const int g = lane >> 4;

  f32x4 acc0[8], acc1[8];
#pragma unroll
  for (int ct = 0; ct < 8; ++ct) {
    const float bv = bsv[ct * 16 + rlo];
    acc0[ct] = (f32x4){bv, bv, bv, bv};
    acc1[ct] = (f32x4){bv, bv, bv, bv};
  }

  const int rA0 = min(row0 + rlo, n - 1);
  const int rA1 = min(row0 + 16 + rlo, n - 1);
  const int x7 = rlo & 7;                      // == c&7 for c = ct*16+rlo

#pragma unroll
  for (int kc = 0; kc < 4; ++kc) {
    const int k0 = kc * 32 + g * 8;
    const bf16x8 as0 = *(const bf16x8*)(fb + (size_t)rA0 * 128 + k0);
    const bf16x8 ag0 = *(const bf16x8*)(aggu + (size_t)rA0 * 128 + (k0 >> 1));
    const bf16x8 as1 = *(const bf16x8*)(fb + (size_t)rA1 * 128 + k0);
    const bf16x8 ag1 = *(const bf16x8*)(aggu + (size_t)rA1 * 128 + (k0 >> 1));
    const int slot = (kc * 4 + g) ^ x7;
#pragma unroll
    for (int ct = 0; ct < 8; ++ct) {
      const int c = ct * 16 + rlo;
      const bf16x8 bsw = u4_to_bf(wlds[c * 32 + slot]);
      const bf16x8 bnw = u4_to_bf(wlds[c * 32 + 16 + slot]);
      acc0[ct] = __builtin_amdgcn_mfma_f32_16x16x32_bf16(as0, bsw, acc0[ct], 0, 0, 0);
      acc0[ct] = __builtin_amdgcn_mfma_f32_16x16x32_bf16(ag0, bnw, acc0[ct], 0, 0, 0);
      acc1[ct] = __builtin_amdgcn_mfma_f32_16x16x32_bf16(as1, bsw, acc1[ct], 0, 0, 0);
      acc1[ct] = __builtin_amdgcn_mfma_f32_16x16x32_bf16(ag1, bnw, acc1[ct], 0, 0, 0);
    }
  }

  // C/D layout: col = ct*16 + (lane&15), row = (lane>>4)*4 + j   [m89-verified]
#pragma unroll
  for (int ct = 0; ct < 8; ++ct) {
#pragma unroll
    for (int j = 0; j < 4; ++j) {
      const int r0 = row0 + g * 4 + j;
      if (r0 < n) out[(size_t)r0 * 128 + ct * 16 + rlo] = acc0[ct][j];
      const int r1 = row0 + 16 + g * 4 + j;
      if (r1 < n) out[(size_t)r1 * 128 + ct * 16 + rlo] = acc1[ct][j];
    }
  }
}

extern "C" void kernel_launch(void* const* d_in, const int* in_sizes, int n_in,
                              void* d_out, int out_size, void* d_ws, size_t ws_size,
                              hipStream_t stream) {
  const float* feat = (const float*)d_in[0];
  const int* src = (const int*)d_in[1];
  const int* dst = (const int*)d_in[2];
  const float* ew = (const float*)d_in[3];
  const float* Wn = (const float*)d_in[4];
  const float* Ws = (const float*)d_in[5];
  const float* bs = (const float*)d_in[6];
  const int n = in_sizes[0] / 128;
  const int E = in_sizes[1];
  float* out = (float*)d_out;
  unsigned* aggu = (unsigned*)d_out;

  const int nbins = (n + 255) >> 8;

  // ws: colw 6.4 | cnt ~0.2 | ovf 0.5 | binbuf 8 | fb 12.8 | fbq 6.4 | W 0.06
  char* w = (char*)d_ws;
  size_t off_colw = 0;
  size_t off_cnt = (off_colw + (size_t)n * CAP * 4 + 255) & ~(size_t)255;
  size_t off_ovf = (off_cnt + (size_t)(n + 1 + 256) * 4 + 255) & ~(size_t)255;
  size_t off_binbuf = (off_ovf + (size_t)OVFCAP * 8 + 255) & ~(size_t)255;
  size_t off_fb = (off_binbuf + (size_t)256 * BSTRIDE * 8 + 255) & ~(size_t)255;
  size_t off_fbq = (off_fb + (size_t)n * 64 * 4 + 255) & ~(size_t)255;
  size_t off_wsb = (off_fbq + (size_t)n * 32 * 4 + 255) & ~(size_t)255;
  size_t off_wnb = off_wsb + 8192 * 4;
  unsigned* colw = (unsigned*)(w + off_colw);
  int* cnt = (int*)(w + off_cnt);
  int* ovfcnt = cnt + n;
  int* gbin = cnt + n + 1;                  // 256 ints
  uint2* ovf = (uint2*)(w + off_ovf);
  uint2* binbuf = (uint2*)(w + off_binbuf);
  unsigned* fb = (unsigned*)(w + off_fb);
  unsigned* fbq = (unsigned*)(w + off_fbq);
  unsigned* wsb = (unsigned*)(w + off_wsb);
  unsigned* wnb = (unsigned*)(w + off_wnb);

  zero_kernel<<<1, 512, 0, stream>>>(ovfcnt);   // ovfcnt + gbin (257 ints)

  const int nchunk = (E + BINCHUNK - 1) / BINCHUNK;
  prep_kernel<<<nchunk + 1024 + 32, 256, 0, stream>>>(
      src, dst, ew, gbin, binbuf, ovfcnt, ovf, E,
      feat, fb, fbq, n * 32, Ws, Wn, wsb, wnb, nchunk);

  bucket_kernel<<<nbins, 256, 0, stream>>>(gbin, binbuf, cnt, colw, ovfcnt, ovf, n);

  // agg (packed bf16) -> d_out rows; overflow folded in
  gather_kernel<<<(n * 64 + 255) / 256, 256, 0, stream>>>(
      fbq, cnt, colw, ovfcnt, ovf, aggu, n);

  // fused: out = feat@Ws.T + b + agg@Wn.T   (in-place on d_out)
  const int nblocks = (n + 127) / 128;
  fused_gemm_kernel<<<nblocks, 256, 0, stream>>>(
      (const ushort*)fb, aggu, (const uint4*)wsb, (const uint4*)wnb, bs, out, n);
}